// Round 6
// baseline (813.218 us; speedup 1.0000x reference)
//
#include <hip/hip_runtime.h>
#include <hip/hip_fp16.h>
#include <math.h>

#define N_ 4
#define C_ 31
#define H_ 128
#define W_ 128
#define TOTAL (N_*C_*H_*W_)
#define CV_ (C_*H_*W_)
#define PI_F 3.14159265358979f
#define RHO_F 1.05f
#define INV_RHO (1.0f/1.05f)
#define NORM2 (1.0f/16384.0f)    // 1/(128*128)

__device__ __forceinline__ float2 cmul(float2 a, float2 b){
  return make_float2(a.x*b.x - a.y*b.y, a.x*b.y + a.y*b.x);
}
__device__ __forceinline__ float2 shflx(float2 v, int m){
  return make_float2(__shfl_xor(v.x, m, 64), __shfl_xor(v.y, m, 64));
}
__device__ __forceinline__ float shrinkf(float x, float t){
  return copysignf(fmaxf(fabsf(x) - t, 0.0f), x);
}
__device__ __forceinline__ uint packh2(float2 v){
  union{__half2 h2; uint u;} cv; cv.h2 = __floats2half2_rn(v.x, v.y); return cv.u;
}
__device__ __forceinline__ float2 unpackh2(uint u){
  union{uint u; __half2 h2;} cv; cv.u = u; return __half22float2(cv.h2);
}
// V recurrence (non-first): vnew = shrink((1+1/rho)*D - vold/rho, thr) + (vold - D)/rho
__device__ __forceinline__ float2 vupd(float2 D, __half2 vold, float thr){
  float2 vo = __half22float2(vold);
  const float aa = 1.0f + INV_RHO;
  return make_float2(
    shrinkf(aa*D.x - vo.x*INV_RHO, thr) + (vo.x - D.x)*INV_RHO,
    shrinkf(aa*D.y - vo.y*INV_RHO, thr) + (vo.y - D.y)*INV_RHO);
}

__device__ __forceinline__ void make_tw(float2* tw, int t, float sgn, bool sel){
  float s, c;
  sincosf(sgn * 2.0f * PI_F * (float)t / 128.0f, &s, &c);
  tw[0] = make_float2(c, s);
  #pragma unroll
  for (int i = 1; i < 7; ++i){
    int sp = 64 >> i;
    float ang = (!sel || (t & sp)) ? sgn * 2.0f * PI_F * (float)(t & (sp-1)) / (float)(2*sp) : 0.0f;
    sincosf(ang, &s, &c);
    tw[i] = make_float2(c, s);
  }
}

// Forward DIF FFT-128 over a wave; outputs bit-reversed positions.
__device__ __forceinline__ void fft128_fwd(float2& a, float2& b, const float2* twf, int t){
  float2 u = make_float2(a.x + b.x, a.y + b.y);
  float2 d = make_float2(a.x - b.x, a.y - b.y);
  float2 v = cmul(d, twf[0]);
  #pragma unroll
  for (int i = 1; i < 7; ++i){
    int sp = 64 >> i;
    bool up = (t & sp) != 0;
    float2 pu = shflx(u, sp);
    float2 du = up ? make_float2(pu.x - u.x, pu.y - u.y)
                   : make_float2(u.x + pu.x, u.y + pu.y);
    u = cmul(du, twf[i]);
    float2 pv = shflx(v, sp);
    float2 dv = up ? make_float2(pv.x - v.x, pv.y - v.y)
                   : make_float2(v.x + pv.x, v.y + pv.y);
    v = cmul(dv, twf[i]);
  }
  a = u; b = v;
}

// Inverse DIT FFT-128 (unnormalized): bit-reversed in, natural out.
__device__ __forceinline__ void fft128_inv(float2& a, float2& b, const float2* twi, int t){
  float2 u = a, v = b;
  #pragma unroll
  for (int i = 6; i >= 1; --i){
    int sp = 64 >> i;
    bool up = (t & sp) != 0;
    float2 pu = shflx(u, sp);
    float2 e  = up ? pu : u;
    float2 o  = up ? u  : pu;
    float2 wo = cmul(o, twi[i]);
    u = up ? make_float2(e.x - wo.x, e.y - wo.y)
           : make_float2(e.x + wo.x, e.y + wo.y);
    float2 pv = shflx(v, sp);
    float2 ev = up ? pv : v;
    float2 ov = up ? v  : pv;
    float2 wv = cmul(ov, twi[i]);
    v = up ? make_float2(ev.x - wv.x, ev.y - wv.y)
           : make_float2(ev.x + wv.x, ev.y + wv.y);
  }
  float2 tv = cmul(v, twi[0]);
  a = make_float2(u.x + tv.x, u.y + tv.y);
  b = make_float2(u.x - tv.x, u.y - tv.y);
}

// K0: one-time pack: YWp[pair][chw] = (half2(y0,iw0), half2(y1,iw1))
__global__ __launch_bounds__(256) void kern_pack(const float* __restrict__ Y,
    const float* __restrict__ W, uint2* __restrict__ YWp)
{
  int i = blockIdx.x * 256 + threadIdx.x;    // [0, 2*CV_)
  int pair = i / CV_, j = i - pair*CV_;
  long b0 = (long)(2*pair)*CV_ + j, b1 = b0 + CV_;
  union{__half2 h2; uint u;} a, b;
  a.h2 = __floats2half2_rn(Y[b0], W[b0]);
  b.h2 = __floats2half2_rn(Y[b1], W[b1]);
  YWp[i] = make_uint2(a.u, b.u);
}

// K1: first iteration: V0 = shrink(D Y), numer0 (Q0=Y), W-FFT -> A0. Writes V0.
// Block = (pair, c, h-tile of 8), 256 threads = 4 waves, 2 rows/wave.
__global__ __launch_bounds__(256) void kern_fwd0(const float* __restrict__ Y,
    __half2* __restrict__ Vho, __half2* __restrict__ Vvo, __half2* __restrict__ Vso,
    __half2* __restrict__ A, float thr)
{
  __shared__ float2 zbuf[26][128];
  __shared__ uint   zs[25][128];   // rows 0..7 sVh, 8..16 sVv, 17..24 tbuf
  int tid = threadIdx.x, lane = tid & 63, wv = tid >> 6;
  int b = blockIdx.x;
  int ht = b & 15, c = (b >> 4) % C_, pair = b / (16*C_);
  int h0 = ht * 8;
  int cm1 = c ? c-1 : C_-1, cp1 = (c == C_-1) ? 0 : c+1;
  long v0 = (long)(2*pair)*CV_, v1 = v0 + CV_;

  // stage z rows (z = Y): u<10: (c, h0-1+u); u<18: (c-1, h0+u-10); else (c+1, h0+u-18)
  for (int u = wv; u < 26; u += 4){
    int cc, h;
    if (u < 10){ cc = c; h = (h0 - 1 + u) & (H_-1); }
    else if (u < 18){ cc = cm1; h = h0 + u - 10; }
    else { cc = cp1; h = h0 + u - 18; }
    long rb = ((long)cc*H_ + h)*W_;
    #pragma unroll
    for (int e = 0; e < 2; ++e){
      int w = lane + 64*e;
      zbuf[u][w] = make_float2(Y[v0+rb+w], Y[v1+rb+w]);
    }
  }
  __syncthreads();

  float2 q[2][2], vs[2][2], vsm[2][2];
  #pragma unroll
  for (int r = 0; r < 2; ++r){
    int i = wv + 4*r, h = h0 + i;
    long pv = ((long)(pair*C_ + c)*H_ + h)*W_;
    #pragma unroll
    for (int e = 0; e < 2; ++e){
      int w = lane + 64*e;
      float2 z0 = zbuf[i+1][w];
      float2 zw = zbuf[i+1][(w+1)&(W_-1)];
      float2 zh = zbuf[i+2][w];
      float2 zc = zbuf[18+i][w];
      float2 zm = zbuf[10+i][w];
      float2 vh = make_float2(shrinkf(z0.x-zw.x,thr), shrinkf(z0.y-zw.y,thr));
      float2 vv = make_float2(shrinkf(z0.x-zh.x,thr), shrinkf(z0.y-zh.y,thr));
      float2 vsl= make_float2(shrinkf(z0.x-zc.x,thr), shrinkf(z0.y-zc.y,thr));
      vsm[r][e] = make_float2(shrinkf(zm.x-z0.x,thr), shrinkf(zm.y-z0.y,thr));
      union{float2 f; __half2 h2;} cv;
      Vho[pv+w] = __floats2half2_rn(vh.x, vh.y);
      Vvo[pv+w] = __floats2half2_rn(vv.x, vv.y);
      Vso[pv+w] = __floats2half2_rn(vsl.x, vsl.y);
      (void)cv;
      zs[i][w]   = packh2(vh);
      zs[9+i][w] = packh2(vv);
      vs[r][e] = vsl;
      q[r][e]  = z0;               // Q0 = Y
    }
  }
  if (wv == 0){
    long pvh = ((long)(pair*C_ + c)*H_ + ((h0+H_-1)&(H_-1)))*W_;
    (void)pvh;
    #pragma unroll
    for (int e = 0; e < 2; ++e){
      int w = lane + 64*e;
      float2 z0 = zbuf[0][w], zh = zbuf[1][w];
      float2 vvm = make_float2(shrinkf(z0.x-zh.x,thr), shrinkf(z0.y-zh.y,thr));
      zs[8][w] = packh2(vvm);
    }
  }
  __syncthreads();

  float2 twf[7]; make_tw(twf, lane, -1.0f, true);
  #pragma unroll
  for (int r = 0; r < 2; ++r){
    int i = wv + 4*r;
    float2 nm[2];
    #pragma unroll
    for (int e = 0; e < 2; ++e){
      int w = lane + 64*e;
      float2 vh  = unpackh2(zs[i][w]);
      float2 vhm = unpackh2(zs[i][(w+W_-1)&(W_-1)]);
      float2 vv  = unpackh2(zs[9+i][w]);
      float2 vvm = unpackh2(zs[8+i][w]);
      nm[e] = make_float2(q[r][e].x + (vh.x-vhm.x) + (vv.x-vvm.x) + (vs[r][e].x - vsm[r][e].x),
                          q[r][e].y + (vh.y-vhm.y) + (vv.y-vvm.y) + (vs[r][e].y - vsm[r][e].y));
    }
    fft128_fwd(nm[0], nm[1], twf, lane);
    zs[17+i][lane]    = packh2(nm[0]);
    zs[17+i][lane+64] = packh2(nm[1]);
  }
  __syncthreads();
  int4* A4 = (int4*)A;
  int p = tid >> 1, hq = tid & 1;
  union{int4 v; uint e[4];} u;
  #pragma unroll
  for (int j = 0; j < 4; ++j) u.e[j] = zs[17 + 4*hq + j][p];
  A4[((long)(pair*W_ + p)*C_ + c)*32 + 2*ht + hq] = u.v;
}

// K2: H-FFT fwd + 25-tap circulant c-solve + H-FFT inv, per (pair, w) slab. In place.
__global__ __launch_bounds__(1024) void kern_CH(__half2* __restrict__ A)
{
  __shared__ float2 slab[C_][H_];
  int tid = threadIdx.x, lane = tid & 63, wv = tid >> 6;
  int bid = blockIdx.x;                 // pair*128 + w
  int w = bid & (W_-1);
  const int4* g4 = (const int4*)(A + (long)bid * C_ * H_);

  if (tid < 992){
    union { int4 v; __half2 e[4]; } u;
    u.v = g4[tid];
    int c = tid >> 5, hb = (tid & 31) << 2;
    #pragma unroll
    for (int j = 0; j < 4; ++j) slab[c][hb+j] = __half22float2(u.e[j]);
  }
  float2 twf[7], twi[7];
  make_tw(twf, lane, -1.0f, true);
  make_tw(twi, lane, +1.0f, false);
  __syncthreads();

  #pragma unroll
  for (int rr = 0; rr < 2; ++rr){
    int c = wv + 16*rr;
    if (c < C_){
      float2 a = slab[c][lane], b = slab[c][lane+64];
      fft128_fwd(a, b, twf, lane);
      slab[c][lane] = a; slab[c][lane+64] = b;
    }
  }
  __syncthreads();

  {
    int col = tid & (H_-1), cb = tid >> 7, c0 = cb * 4;
    int fh = __brev(col) >> 25;
    int fw = __brev(w)   >> 25;
    float dh = 2.0f - 2.0f * cosf(2.0f * PI_F * (float)fh / 128.0f);
    float dw = 2.0f - 2.0f * cosf(2.0f * PI_F * (float)fw / 128.0f);
    float beta = 1.0f + dh + dw;
    float a2 = beta + 2.0f;
    float s  = sqrtf(a2*a2 - 4.0f);
    float rg = (a2 - s) * 0.5f;
    float gt[13];
    gt[0] = NORM2 / s;
    #pragma unroll
    for (int t = 1; t < 13; ++t) gt[t] = gt[t-1] * rg;

    float2 win[28];
    #pragma unroll
    for (int i = 0; i < 28; ++i){
      int ci = c0 - 12 + i;
      if (ci < 0) ci += C_;
      if (ci >= C_) ci -= C_;
      win[i] = slab[ci][col];
    }
    float2 out[4];
    #pragma unroll
    for (int j = 0; j < 4; ++j){
      float ox = 0.0f, oy = 0.0f;
      #pragma unroll
      for (int t = -12; t <= 12; ++t){
        float gv = gt[t < 0 ? -t : t];
        float2 xv = win[j + 12 - t];
        ox += gv * xv.x;
        oy += gv * xv.y;
      }
      out[j] = make_float2(ox, oy);
    }
    __syncthreads();
    #pragma unroll
    for (int j = 0; j < 4; ++j){
      int c = c0 + j;
      if (c < C_) slab[c][col] = out[j];
    }
  }
  __syncthreads();

  #pragma unroll
  for (int rr = 0; rr < 2; ++rr){
    int c = wv + 16*rr;
    if (c < C_){
      float2 a = slab[c][lane], b = slab[c][lane+64];
      fft128_inv(a, b, twi, lane);
      slab[c][lane] = a; slab[c][lane+64] = b;
    }
  }
  __syncthreads();
  int4* go4 = (int4*)(A + (long)bid * C_ * H_);
  if (tid < 992){
    int c = tid >> 5, hb = (tid & 31) << 2;
    union { int4 v; __half2 e[4]; } u;
    #pragma unroll
    for (int j = 0; j < 4; ++j){
      float2 f = slab[c][hb+j];
      u.e[j] = __floats2half2_rn(f.x, f.y);
    }
    go4[tid] = u.v;
  }
}

// K3: fused iteration tail+head: iW-FFT (own 8 rows + 18 halo rows) -> z (LDS) ->
// X/G1/Q update (mu_t) -> V_{t+1} (thr_{t+1}) -> numer_{t+1} -> W-FFT -> A_{t+1}.
__global__ __launch_bounds__(256) void kern_CA(
    const __half2* __restrict__ Ain, __half2* __restrict__ Aout,
    const __half2* __restrict__ Vhi, const __half2* __restrict__ Vvi, const __half2* __restrict__ Vsi,
    __half2* __restrict__ Vho, __half2* __restrict__ Vvo, __half2* __restrict__ Vso,
    const uint2* __restrict__ YWp, __half2* __restrict__ G1,
    float mu, float thrn, float invmun, int firstG)
{
  __shared__ float2 zbuf[26][128];
  __shared__ uint   zs[32][128];   // phase0/1: staged spectra; later rows 0..7 sVh, 8..16 sVv, 17..24 tbuf
  int tid = threadIdx.x, lane = tid & 63, wv = tid >> 6;
  int b = blockIdx.x;
  int ht = b & 15, c = (b >> 4) % C_, pair = b / (16*C_);
  int h0 = ht * 8;
  int cm1 = c ? c-1 : C_-1, cp1 = (c == C_-1) ? 0 : c+1;

  // phase 0: stage A (fp16 spectra) with halos
  const int4* A4 = (const int4*)Ain;
  #pragma unroll
  for (int k = 0; k < 4; ++k){
    int i = tid + 256*k;               // 0..1023
    int w = i & 127;
    int quad, cc, dr;
    if (i < 512){ int qi = i >> 7; quad = (2*ht - 1 + qi) & 31; cc = c;   dr = 4*qi; }
    else if (i < 768){ int qi = (i >> 7) & 1; quad = 2*ht + qi; cc = cm1; dr = 16 + 4*qi; }
    else { int qi = (i >> 7) & 1; quad = 2*ht + qi; cc = cp1; dr = 24 + 4*qi; }
    union{int4 v; uint e[4];} u;
    u.v = A4[((long)(pair*W_ + w)*C_ + cc)*32 + quad];
    #pragma unroll
    for (int j = 0; j < 4; ++j) zs[dr+j][w] = u.e[j];
  }
  __syncthreads();

  // phase 1: inverse W-FFT of the 26 needed rows -> zbuf
  float2 twi[7]; make_tw(twi, lane, +1.0f, false);
  for (int uu = wv; uu < 26; uu += 4){
    int zr = (uu < 10) ? (uu + 3) : (uu + 6);
    float2 a = unpackh2(zs[zr][lane]);
    float2 bb = unpackh2(zs[zr][lane+64]);
    fft128_inv(a, bb, twi, lane);
    zbuf[uu][lane] = a; zbuf[uu][lane+64] = bb;
  }
  __syncthreads();

  // phase 2a: V_{t+1} (own + halo), X/G1/Q
  float2 q[2][2], vs[2][2], vsm[2][2];
  #pragma unroll
  for (int r = 0; r < 2; ++r){
    int i = wv + 4*r, h = h0 + i;
    long pv  = ((long)(pair*C_ + c  )*H_ + h)*W_;
    long pvm = ((long)(pair*C_ + cm1)*H_ + h)*W_;
    #pragma unroll
    for (int e = 0; e < 2; ++e){
      int w = lane + 64*e;
      float2 z0 = zbuf[i+1][w];
      float2 zw = zbuf[i+1][(w+1)&(W_-1)];
      float2 zh = zbuf[i+2][w];
      float2 zc = zbuf[18+i][w];
      float2 zm = zbuf[10+i][w];
      float2 vh  = vupd(make_float2(z0.x-zw.x, z0.y-zw.y), Vhi[pv+w], thrn);
      float2 vv  = vupd(make_float2(z0.x-zh.x, z0.y-zh.y), Vvi[pv+w], thrn);
      float2 vsl = vupd(make_float2(z0.x-zc.x, z0.y-zc.y), Vsi[pv+w], thrn);
      vsm[r][e]  = vupd(make_float2(zm.x-z0.x, zm.y-z0.y), Vsi[pvm+w], thrn);
      Vho[pv+w] = __floats2half2_rn(vh.x, vh.y);
      Vvo[pv+w] = __floats2half2_rn(vv.x, vv.y);
      Vso[pv+w] = __floats2half2_rn(vsl.x, vsl.y);
      zs[i][w]   = packh2(vh);
      zs[9+i][w] = packh2(vv);
      vs[r][e] = vsl;
      // X/G1/Q
      uint2 yw = YWp[pv+w];
      union{uint u; __half2 h2;} c0, c1; c0.u = yw.x; c1.u = yw.y;
      float2 a0 = __half22float2(c0.h2);   // (y, iw) vol0
      float2 a1 = __half22float2(c1.h2);   // (y, iw) vol1
      float2 g1 = firstG ? make_float2(0.0f, 0.0f) : __half22float2(G1[pv+w]);
      float x0 = (a0.y*a0.x + mu*z0.x - g1.x) / (a0.y + mu);
      float x1 = (a1.y*a1.x + mu*z0.y - g1.y) / (a1.y + mu);
      float g10 = g1.x + mu*(x0 - z0.x);
      float g11 = g1.y + mu*(x1 - z0.y);
      G1[pv+w] = __floats2half2_rn(g10, g11);
      q[r][e] = make_float2(x0 + g10*invmun, x1 + g11*invmun);
    }
  }
  if (wv == 0){
    long pvh = ((long)(pair*C_ + c)*H_ + ((h0+H_-1)&(H_-1)))*W_;
    #pragma unroll
    for (int e = 0; e < 2; ++e){
      int w = lane + 64*e;
      float2 z0 = zbuf[0][w], zh = zbuf[1][w];
      float2 vvm = vupd(make_float2(z0.x-zh.x, z0.y-zh.y), Vvi[pvh+w], thrn);
      zs[8][w] = packh2(vvm);
    }
  }
  __syncthreads();

  // phase 2b: numer + forward W-FFT -> tbuf
  float2 twf[7]; make_tw(twf, lane, -1.0f, true);
  #pragma unroll
  for (int r = 0; r < 2; ++r){
    int i = wv + 4*r;
    float2 nm[2];
    #pragma unroll
    for (int e = 0; e < 2; ++e){
      int w = lane + 64*e;
      float2 vh  = unpackh2(zs[i][w]);
      float2 vhm = unpackh2(zs[i][(w+W_-1)&(W_-1)]);
      float2 vv  = unpackh2(zs[9+i][w]);
      float2 vvm = unpackh2(zs[8+i][w]);
      nm[e] = make_float2(q[r][e].x + (vh.x-vhm.x) + (vv.x-vvm.x) + (vs[r][e].x - vsm[r][e].x),
                          q[r][e].y + (vh.y-vhm.y) + (vv.y-vvm.y) + (vs[r][e].y - vsm[r][e].y));
    }
    fft128_fwd(nm[0], nm[1], twf, lane);
    zs[17+i][lane]    = packh2(nm[0]);
    zs[17+i][lane+64] = packh2(nm[1]);
  }
  __syncthreads();
  int4* Ao4 = (int4*)Aout;
  int p = tid >> 1, hq = tid & 1;
  union{int4 v; uint e[4];} uo;
  #pragma unroll
  for (int j = 0; j < 4; ++j) uo.e[j] = zs[17 + 4*hq + j][p];
  Ao4[((long)(pair*W_ + p)*C_ + c)*32 + 2*ht + hq] = uo.v;
}

// K4: final: iW-FFT own rows only -> Z fp32.
__global__ __launch_bounds__(256) void kern_last(const __half2* __restrict__ A,
    float* __restrict__ Z)
{
  __shared__ uint zs[8][128];
  int tid = threadIdx.x, lane = tid & 63, wv = tid >> 6;
  int b = blockIdx.x;
  int ht = b & 15, c = (b >> 4) % C_, pair = b / (16*C_);
  int h0 = ht * 8;
  const int4* A4 = (const int4*)A;
  {
    int p = tid >> 1, hq = tid & 1;
    union{int4 v; uint e[4];} u;
    u.v = A4[((long)(pair*W_ + p)*C_ + c)*32 + 2*ht + hq];
    #pragma unroll
    for (int j = 0; j < 4; ++j) zs[4*hq + j][p] = u.e[j];
  }
  __syncthreads();
  float2 twi[7]; make_tw(twi, lane, +1.0f, false);
  long v0 = (long)(2*pair)*CV_, v1 = v0 + CV_;
  #pragma unroll
  for (int r = 0; r < 2; ++r){
    int i = wv + 4*r, h = h0 + i;
    float2 a = unpackh2(zs[i][lane]);
    float2 bb = unpackh2(zs[i][lane+64]);
    fft128_inv(a, bb, twi, lane);
    long rb = ((long)c*H_ + h)*W_;
    Z[v0+rb+lane]    = a.x;  Z[v1+rb+lane]    = a.y;
    Z[v0+rb+lane+64] = bb.x; Z[v1+rb+lane+64] = bb.y;
  }
}

extern "C" void kernel_launch(void* const* d_in, const int* in_sizes, int n_in,
                              void* d_out, int out_size, void* d_ws, size_t ws_size,
                              hipStream_t stream)
{
  const float* Y   = (const float*)d_in[0];
  const float* inW = (const float*)d_in[1];
  float* Z = (float*)d_out;

  const int HT = TOTAL/2;   // half2/uint2 element counts per field
  uint2*   YWp = (uint2*)d_ws;
  __half2* G1  = (__half2*)(YWp + HT);
  __half2* Vh0 = G1  + HT;
  __half2* Vv0 = Vh0 + HT;
  __half2* Vs0 = Vv0 + HT;
  __half2* Vh1 = Vs0 + HT;
  __half2* Vv1 = Vh1 + HT;
  __half2* Vs1 = Vv1 + HT;
  __half2* A0  = Vs1 + HT;
  __half2* A1  = A0  + HT;
  __half2* Vh[2] = {Vh0, Vh1};
  __half2* Vv[2] = {Vv0, Vv1};
  __half2* Vs[2] = {Vs0, Vs1};
  __half2* Ab[2] = {A0, A1};

  kern_pack<<<dim3(2*CV_/256), dim3(256), 0, stream>>>(Y, inW, YWp);
  kern_fwd0<<<dim3(2*C_*16), dim3(256), 0, stream>>>(Y, Vh0, Vv0, Vs0, A0, 1.0f);

  float mu = 0.1f;
  for (int t = 0; t < 19; ++t){
    kern_CH<<<dim3(2*W_), dim3(1024), 0, stream>>>(Ab[t&1]);
    float mun = mu * RHO_F;
    kern_CA<<<dim3(2*C_*16), dim3(256), 0, stream>>>(
        Ab[t&1], Ab[(t+1)&1],
        Vh[t&1], Vv[t&1], Vs[t&1],
        Vh[(t+1)&1], Vv[(t+1)&1], Vs[(t+1)&1],
        YWp, G1, mu, 0.1f/mun, 1.0f/mun, (t==0) ? 1 : 0);
    mu = mun;
  }
  kern_CH<<<dim3(2*W_), dim3(1024), 0, stream>>>(Ab[1]);
  kern_last<<<dim3(2*C_*16), dim3(256), 0, stream>>>(Ab[1], Z);
}

// Round 7
// 784.544 us; speedup vs baseline: 1.0365x; 1.0365x over previous
//
#include <hip/hip_runtime.h>
#include <hip/hip_fp16.h>
#include <math.h>

#define N_ 4
#define C_ 31
#define H_ 128
#define W_ 128
#define TOTAL (N_*C_*H_*W_)
#define CV_ (C_*H_*W_)
#define PI_F 3.14159265358979f
#define RHO_F 1.05f
#define INV_RHO (1.0f/1.05f)
#define NORM2 (1.0f/16384.0f)    // 1/(128*128)

__device__ __forceinline__ float2 cmul(float2 a, float2 b){
  return make_float2(a.x*b.x - a.y*b.y, a.x*b.y + a.y*b.x);
}
__device__ __forceinline__ float2 shflx(float2 v, int m){
  return make_float2(__shfl_xor(v.x, m, 64), __shfl_xor(v.y, m, 64));
}
__device__ __forceinline__ float shrinkf(float x, float t){
  return copysignf(fmaxf(fabsf(x) - t, 0.0f), x);
}
__device__ __forceinline__ uint packh2(float2 v){
  union{__half2 h2; uint u;} cv; cv.h2 = __floats2half2_rn(v.x, v.y); return cv.u;
}
__device__ __forceinline__ float2 unpackh2(uint u){
  union{uint uu; __half2 h2;} cv; cv.uu = u; return __half22float2(cv.h2);
}
// V recurrence (non-first): vnew = shrink((1+1/rho)*D - vold/rho, thr) + (vold - D)/rho
__device__ __forceinline__ float2 vupd(float2 D, __half2 vold, float thr){
  float2 vo = __half22float2(vold);
  const float aa = 1.0f + INV_RHO;
  return make_float2(
    shrinkf(aa*D.x - vo.x*INV_RHO, thr) + (vo.x - D.x)*INV_RHO,
    shrinkf(aa*D.y - vo.y*INV_RHO, thr) + (vo.y - D.y)*INV_RHO);
}
__device__ __forceinline__ void load_tw(const float2* __restrict__ lut, float2* tw, int lane){
  #pragma unroll
  for (int i = 0; i < 7; ++i) tw[i] = lut[i*64 + lane];
}

// Forward DIF FFT-128 over a wave; outputs bit-reversed positions.
__device__ __forceinline__ void fft128_fwd(float2& a, float2& b, const float2* twf, int t){
  float2 u = make_float2(a.x + b.x, a.y + b.y);
  float2 d = make_float2(a.x - b.x, a.y - b.y);
  float2 v = cmul(d, twf[0]);
  #pragma unroll
  for (int i = 1; i < 7; ++i){
    int sp = 64 >> i;
    bool up = (t & sp) != 0;
    float2 pu = shflx(u, sp);
    float2 du = up ? make_float2(pu.x - u.x, pu.y - u.y)
                   : make_float2(u.x + pu.x, u.y + pu.y);
    u = cmul(du, twf[i]);
    float2 pv = shflx(v, sp);
    float2 dv = up ? make_float2(pv.x - v.x, pv.y - v.y)
                   : make_float2(v.x + pv.x, v.y + pv.y);
    v = cmul(dv, twf[i]);
  }
  a = u; b = v;
}

// Inverse DIT FFT-128 (unnormalized): bit-reversed in, natural out.
__device__ __forceinline__ void fft128_inv(float2& a, float2& b, const float2* twi, int t){
  float2 u = a, v = b;
  #pragma unroll
  for (int i = 6; i >= 1; --i){
    int sp = 64 >> i;
    bool up = (t & sp) != 0;
    float2 pu = shflx(u, sp);
    float2 e  = up ? pu : u;
    float2 o  = up ? u  : pu;
    float2 wo = cmul(o, twi[i]);
    u = up ? make_float2(e.x - wo.x, e.y - wo.y)
           : make_float2(e.x + wo.x, e.y + wo.y);
    float2 pv = shflx(v, sp);
    float2 ev = up ? pv : v;
    float2 ov = up ? v  : pv;
    float2 wv = cmul(ov, twi[i]);
    v = up ? make_float2(ev.x - wv.x, ev.y - wv.y)
           : make_float2(ev.x + wv.x, ev.y + wv.y);
  }
  float2 tv = cmul(v, twi[0]);
  a = make_float2(u.x + tv.x, u.y + tv.y);
  b = make_float2(u.x - tv.x, u.y - tv.y);
}

// K-1: one-time twiddle/demo LUT init. 1 block, 128 threads.
__global__ __launch_bounds__(128) void kern_init(float2* __restrict__ twf_lut,
    float2* __restrict__ twi_lut, float* __restrict__ dtab)
{
  int t = threadIdx.x;
  if (t < 64){
    float s, c;
    sincosf(-2.0f*PI_F*(float)t/128.0f, &s, &c);
    twf_lut[t] = make_float2(c, s);
    sincosf(+2.0f*PI_F*(float)t/128.0f, &s, &c);
    twi_lut[t] = make_float2(c, s);
    #pragma unroll
    for (int i = 1; i < 7; ++i){
      int sp = 64 >> i;
      float angf = (t & sp) ? -2.0f*PI_F*(float)(t&(sp-1))/(float)(2*sp) : 0.0f;
      sincosf(angf, &s, &c);
      twf_lut[i*64 + t] = make_float2(c, s);
      float angi = +2.0f*PI_F*(float)(t&(sp-1))/(float)(2*sp);
      sincosf(angi, &s, &c);
      twi_lut[i*64 + t] = make_float2(c, s);
    }
  }
  dtab[t] = 2.0f - 2.0f*cosf(2.0f*PI_F*(float)t/128.0f);
}

// K0: one-time pack: YWp[pair][chw] = (half2(y0,iw0), half2(y1,iw1))
__global__ __launch_bounds__(256) void kern_pack(const float* __restrict__ Y,
    const float* __restrict__ W, uint2* __restrict__ YWp)
{
  int i = blockIdx.x * 256 + threadIdx.x;    // [0, 2*CV_)
  int pair = i / CV_, j = i - pair*CV_;
  long b0 = (long)(2*pair)*CV_ + j, b1 = b0 + CV_;
  union{__half2 h2; uint u;} a, b;
  a.h2 = __floats2half2_rn(Y[b0], W[b0]);
  b.h2 = __floats2half2_rn(Y[b1], W[b1]);
  YWp[i] = make_uint2(a.u, b.u);
}

// K1: first iteration: V0 = shrink(D Y), numer0 (Q0=Y), W-FFT -> A0. Writes V0.
__global__ __launch_bounds__(256) void kern_fwd0(const float* __restrict__ Y,
    __half2* __restrict__ Vho, __half2* __restrict__ Vvo, __half2* __restrict__ Vso,
    __half2* __restrict__ A, float thr, const float2* __restrict__ twf_lut)
{
  __shared__ float2 zbuf[26][128];
  __shared__ uint   zs[25][128];
  int tid = threadIdx.x, lane = tid & 63, wv = tid >> 6;
  int b = blockIdx.x;
  int ht = b & 15, c = (b >> 4) % C_, pair = b / (16*C_);
  int h0 = ht * 8;
  int cm1 = c ? c-1 : C_-1, cp1 = (c == C_-1) ? 0 : c+1;
  long v0 = (long)(2*pair)*CV_, v1 = v0 + CV_;

  for (int u = wv; u < 26; u += 4){
    int cc, h;
    if (u < 10){ cc = c; h = (h0 - 1 + u) & (H_-1); }
    else if (u < 18){ cc = cm1; h = h0 + u - 10; }
    else { cc = cp1; h = h0 + u - 18; }
    long rb = ((long)cc*H_ + h)*W_;
    #pragma unroll
    for (int e = 0; e < 2; ++e){
      int w = lane + 64*e;
      zbuf[u][w] = make_float2(Y[v0+rb+w], Y[v1+rb+w]);
    }
  }
  __syncthreads();

  float2 q[2][2], vs[2][2], vsm[2][2];
  #pragma unroll
  for (int r = 0; r < 2; ++r){
    int i = wv + 4*r, h = h0 + i;
    long pv = ((long)(pair*C_ + c)*H_ + h)*W_;
    #pragma unroll
    for (int e = 0; e < 2; ++e){
      int w = lane + 64*e;
      float2 z0 = zbuf[i+1][w];
      float2 zw = zbuf[i+1][(w+1)&(W_-1)];
      float2 zh = zbuf[i+2][w];
      float2 zc = zbuf[18+i][w];
      float2 zm = zbuf[10+i][w];
      float2 vh = make_float2(shrinkf(z0.x-zw.x,thr), shrinkf(z0.y-zw.y,thr));
      float2 vv = make_float2(shrinkf(z0.x-zh.x,thr), shrinkf(z0.y-zh.y,thr));
      float2 vsl= make_float2(shrinkf(z0.x-zc.x,thr), shrinkf(z0.y-zc.y,thr));
      vsm[r][e] = make_float2(shrinkf(zm.x-z0.x,thr), shrinkf(zm.y-z0.y,thr));
      Vho[pv+w] = __floats2half2_rn(vh.x, vh.y);
      Vvo[pv+w] = __floats2half2_rn(vv.x, vv.y);
      Vso[pv+w] = __floats2half2_rn(vsl.x, vsl.y);
      zs[i][w]   = packh2(vh);
      zs[9+i][w] = packh2(vv);
      vs[r][e] = vsl;
      q[r][e]  = z0;
    }
  }
  if (wv == 0){
    #pragma unroll
    for (int e = 0; e < 2; ++e){
      int w = lane + 64*e;
      float2 z0 = zbuf[0][w], zh = zbuf[1][w];
      float2 vvm = make_float2(shrinkf(z0.x-zh.x,thr), shrinkf(z0.y-zh.y,thr));
      zs[8][w] = packh2(vvm);
    }
  }
  __syncthreads();

  float2 twf[7]; load_tw(twf_lut, twf, lane);
  #pragma unroll
  for (int r = 0; r < 2; ++r){
    int i = wv + 4*r;
    float2 nm[2];
    #pragma unroll
    for (int e = 0; e < 2; ++e){
      int w = lane + 64*e;
      float2 vh  = unpackh2(zs[i][w]);
      float2 vhm = unpackh2(zs[i][(w+W_-1)&(W_-1)]);
      float2 vv  = unpackh2(zs[9+i][w]);
      float2 vvm = unpackh2(zs[8+i][w]);
      nm[e] = make_float2(q[r][e].x + (vh.x-vhm.x) + (vv.x-vvm.x) + (vs[r][e].x - vsm[r][e].x),
                          q[r][e].y + (vh.y-vhm.y) + (vv.y-vvm.y) + (vs[r][e].y - vsm[r][e].y));
    }
    fft128_fwd(nm[0], nm[1], twf, lane);
    zs[17+i][lane]    = packh2(nm[0]);
    zs[17+i][lane+64] = packh2(nm[1]);
  }
  __syncthreads();
  int4* A4 = (int4*)A;
  int p = tid >> 1, hq = tid & 1;
  union{int4 v; uint e[4];} u;
  #pragma unroll
  for (int j = 0; j < 4; ++j) u.e[j] = zs[17 + 4*hq + j][p];
  A4[((long)(pair*W_ + p)*C_ + c)*32 + 2*ht + hq] = u.v;
}

// K2: H-FFT fwd + 25-tap circulant c-solve + H-FFT inv, per (pair, w) slab. In place.
__global__ __launch_bounds__(1024) void kern_CH(__half2* __restrict__ A,
    const float2* __restrict__ twf_lut, const float2* __restrict__ twi_lut,
    const float* __restrict__ dtab)
{
  __shared__ float2 slab[C_][H_];
  int tid = threadIdx.x, lane = tid & 63, wv = tid >> 6;
  int bid = blockIdx.x;                 // pair*128 + w
  int w = bid & (W_-1);
  const int4* g4 = (const int4*)(A + (long)bid * C_ * H_);

  if (tid < 992){
    union { int4 v; __half2 e[4]; } u;
    u.v = g4[tid];
    int c = tid >> 5, hb = (tid & 31) << 2;
    #pragma unroll
    for (int j = 0; j < 4; ++j) slab[c][hb+j] = __half22float2(u.e[j]);
  }
  float2 twf[7], twi[7];
  load_tw(twf_lut, twf, lane);
  load_tw(twi_lut, twi, lane);
  __syncthreads();

  #pragma unroll
  for (int rr = 0; rr < 2; ++rr){
    int c = wv + 16*rr;
    if (c < C_){
      float2 a = slab[c][lane], b = slab[c][lane+64];
      fft128_fwd(a, b, twf, lane);
      slab[c][lane] = a; slab[c][lane+64] = b;
    }
  }
  __syncthreads();

  {
    int col = tid & (H_-1), cb = tid >> 7, c0 = cb * 4;
    int fh = __brev(col) >> 25;
    int fw = __brev(w)   >> 25;
    float beta = 1.0f + dtab[fh] + dtab[fw];
    float a2 = beta + 2.0f;
    float s  = sqrtf(a2*a2 - 4.0f);
    float rg = (a2 - s) * 0.5f;
    float gt[13];
    gt[0] = NORM2 / s;
    #pragma unroll
    for (int t = 1; t < 13; ++t) gt[t] = gt[t-1] * rg;

    float2 win[28];
    #pragma unroll
    for (int i = 0; i < 28; ++i){
      int ci = c0 - 12 + i;
      if (ci < 0) ci += C_;
      if (ci >= C_) ci -= C_;
      win[i] = slab[ci][col];
    }
    float2 out[4];
    #pragma unroll
    for (int j = 0; j < 4; ++j){
      float ox = 0.0f, oy = 0.0f;
      #pragma unroll
      for (int t = -12; t <= 12; ++t){
        float gv = gt[t < 0 ? -t : t];
        float2 xv = win[j + 12 - t];
        ox += gv * xv.x;
        oy += gv * xv.y;
      }
      out[j] = make_float2(ox, oy);
    }
    __syncthreads();
    #pragma unroll
    for (int j = 0; j < 4; ++j){
      int c = c0 + j;
      if (c < C_) slab[c][col] = out[j];
    }
  }
  __syncthreads();

  #pragma unroll
  for (int rr = 0; rr < 2; ++rr){
    int c = wv + 16*rr;
    if (c < C_){
      float2 a = slab[c][lane], b = slab[c][lane+64];
      fft128_inv(a, b, twi, lane);
      slab[c][lane] = a; slab[c][lane+64] = b;
    }
  }
  __syncthreads();
  int4* go4 = (int4*)(A + (long)bid * C_ * H_);
  if (tid < 992){
    int c = tid >> 5, hb = (tid & 31) << 2;
    union { int4 v; __half2 e[4]; } u;
    #pragma unroll
    for (int j = 0; j < 4; ++j){
      float2 f = slab[c][hb+j];
      u.e[j] = __floats2half2_rn(f.x, f.y);
    }
    go4[tid] = u.v;
  }
}

// K3: fused iteration tail+head: iW-FFT (own 8 rows + 18 halo rows) -> z (LDS) ->
// X/G1/Q update (mu_t) -> V_{t+1} (thr_{t+1}) -> numer_{t+1} -> W-FFT -> A_{t+1}.
__global__ __launch_bounds__(256) void kern_CA(
    const __half2* __restrict__ Ain, __half2* __restrict__ Aout,
    const __half2* __restrict__ Vhi, const __half2* __restrict__ Vvi, const __half2* __restrict__ Vsi,
    __half2* __restrict__ Vho, __half2* __restrict__ Vvo, __half2* __restrict__ Vso,
    const uint2* __restrict__ YWp, __half2* __restrict__ G1,
    float mu, float thrn, float invmun, int firstG,
    const float2* __restrict__ twf_lut, const float2* __restrict__ twi_lut)
{
  __shared__ float2 zbuf[26][128];
  __shared__ uint   zs[32][128];
  int tid = threadIdx.x, lane = tid & 63, wv = tid >> 6;
  int b = blockIdx.x;
  int ht = b & 15, c = (b >> 4) % C_, pair = b / (16*C_);
  int h0 = ht * 8;
  int cm1 = c ? c-1 : C_-1, cp1 = (c == C_-1) ? 0 : c+1;

  // phase 0: stage A (fp16 spectra) with halos
  const int4* A4 = (const int4*)Ain;
  #pragma unroll
  for (int k = 0; k < 4; ++k){
    int i = tid + 256*k;               // 0..1023
    int w = i & 127;
    int quad, cc, dr;
    if (i < 512){ int qi = i >> 7; quad = (2*ht - 1 + qi) & 31; cc = c;   dr = 4*qi; }
    else if (i < 768){ int qi = (i >> 7) & 1; quad = 2*ht + qi; cc = cm1; dr = 16 + 4*qi; }
    else { int qi = (i >> 7) & 1; quad = 2*ht + qi; cc = cp1; dr = 24 + 4*qi; }
    union{int4 v; uint e[4];} u;
    u.v = A4[((long)(pair*W_ + w)*C_ + cc)*32 + quad];
    #pragma unroll
    for (int j = 0; j < 4; ++j) zs[dr+j][w] = u.e[j];
  }
  __syncthreads();

  // phase 1: inverse W-FFT of the 26 needed rows -> zbuf
  float2 twi[7]; load_tw(twi_lut, twi, lane);
  for (int uu = wv; uu < 26; uu += 4){
    int zr = (uu < 10) ? (uu + 3) : (uu + 6);
    float2 a = unpackh2(zs[zr][lane]);
    float2 bb = unpackh2(zs[zr][lane+64]);
    fft128_inv(a, bb, twi, lane);
    zbuf[uu][lane] = a; zbuf[uu][lane+64] = bb;
  }
  __syncthreads();

  // phase 2a: V_{t+1} (own + halo), X/G1/Q
  float2 q[2][2], vs[2][2], vsm[2][2];
  #pragma unroll
  for (int r = 0; r < 2; ++r){
    int i = wv + 4*r, h = h0 + i;
    long pv  = ((long)(pair*C_ + c  )*H_ + h)*W_;
    long pvm = ((long)(pair*C_ + cm1)*H_ + h)*W_;
    #pragma unroll
    for (int e = 0; e < 2; ++e){
      int w = lane + 64*e;
      float2 z0 = zbuf[i+1][w];
      float2 zw = zbuf[i+1][(w+1)&(W_-1)];
      float2 zh = zbuf[i+2][w];
      float2 zc = zbuf[18+i][w];
      float2 zm = zbuf[10+i][w];
      float2 vh  = vupd(make_float2(z0.x-zw.x, z0.y-zw.y), Vhi[pv+w], thrn);
      float2 vv  = vupd(make_float2(z0.x-zh.x, z0.y-zh.y), Vvi[pv+w], thrn);
      float2 vsl = vupd(make_float2(z0.x-zc.x, z0.y-zc.y), Vsi[pv+w], thrn);
      vsm[r][e]  = vupd(make_float2(zm.x-z0.x, zm.y-z0.y), Vsi[pvm+w], thrn);
      Vho[pv+w] = __floats2half2_rn(vh.x, vh.y);
      Vvo[pv+w] = __floats2half2_rn(vv.x, vv.y);
      Vso[pv+w] = __floats2half2_rn(vsl.x, vsl.y);
      zs[i][w]   = packh2(vh);
      zs[9+i][w] = packh2(vv);
      vs[r][e] = vsl;
      uint2 yw = YWp[pv+w];
      union{uint u; __half2 h2;} c0, c1; c0.u = yw.x; c1.u = yw.y;
      float2 a0 = __half22float2(c0.h2);
      float2 a1 = __half22float2(c1.h2);
      float2 g1 = firstG ? make_float2(0.0f, 0.0f) : __half22float2(G1[pv+w]);
      float x0 = (a0.y*a0.x + mu*z0.x - g1.x) / (a0.y + mu);
      float x1 = (a1.y*a1.x + mu*z0.y - g1.y) / (a1.y + mu);
      float g10 = g1.x + mu*(x0 - z0.x);
      float g11 = g1.y + mu*(x1 - z0.y);
      G1[pv+w] = __floats2half2_rn(g10, g11);
      q[r][e] = make_float2(x0 + g10*invmun, x1 + g11*invmun);
    }
  }
  if (wv == 0){
    long pvh = ((long)(pair*C_ + c)*H_ + ((h0+H_-1)&(H_-1)))*W_;
    #pragma unroll
    for (int e = 0; e < 2; ++e){
      int w = lane + 64*e;
      float2 z0 = zbuf[0][w], zh = zbuf[1][w];
      float2 vvm = vupd(make_float2(z0.x-zh.x, z0.y-zh.y), Vvi[pvh+w], thrn);
      zs[8][w] = packh2(vvm);
    }
  }
  __syncthreads();

  // phase 2b: numer + forward W-FFT -> tbuf
  float2 twf[7]; load_tw(twf_lut, twf, lane);
  #pragma unroll
  for (int r = 0; r < 2; ++r){
    int i = wv + 4*r;
    float2 nm[2];
    #pragma unroll
    for (int e = 0; e < 2; ++e){
      int w = lane + 64*e;
      float2 vh  = unpackh2(zs[i][w]);
      float2 vhm = unpackh2(zs[i][(w+W_-1)&(W_-1)]);
      float2 vv  = unpackh2(zs[9+i][w]);
      float2 vvm = unpackh2(zs[8+i][w]);
      nm[e] = make_float2(q[r][e].x + (vh.x-vhm.x) + (vv.x-vvm.x) + (vs[r][e].x - vsm[r][e].x),
                          q[r][e].y + (vh.y-vhm.y) + (vv.y-vvm.y) + (vs[r][e].y - vsm[r][e].y));
    }
    fft128_fwd(nm[0], nm[1], twf, lane);
    zs[17+i][lane]    = packh2(nm[0]);
    zs[17+i][lane+64] = packh2(nm[1]);
  }
  __syncthreads();
  int4* Ao4 = (int4*)Aout;
  int p = tid >> 1, hq = tid & 1;
  union{int4 v; uint e[4];} uo;
  #pragma unroll
  for (int j = 0; j < 4; ++j) uo.e[j] = zs[17 + 4*hq + j][p];
  Ao4[((long)(pair*W_ + p)*C_ + c)*32 + 2*ht + hq] = uo.v;
}

// K4: final: iW-FFT own rows only -> Z fp32.
__global__ __launch_bounds__(256) void kern_last(const __half2* __restrict__ A,
    float* __restrict__ Z, const float2* __restrict__ twi_lut)
{
  __shared__ uint zs[8][128];
  int tid = threadIdx.x, lane = tid & 63, wv = tid >> 6;
  int b = blockIdx.x;
  int ht = b & 15, c = (b >> 4) % C_, pair = b / (16*C_);
  int h0 = ht * 8;
  const int4* A4 = (const int4*)A;
  {
    int p = tid >> 1, hq = tid & 1;
    union{int4 v; uint e[4];} u;
    u.v = A4[((long)(pair*W_ + p)*C_ + c)*32 + 2*ht + hq];
    #pragma unroll
    for (int j = 0; j < 4; ++j) zs[4*hq + j][p] = u.e[j];
  }
  __syncthreads();
  float2 twi[7]; load_tw(twi_lut, twi, lane);
  long v0 = (long)(2*pair)*CV_, v1 = v0 + CV_;
  #pragma unroll
  for (int r = 0; r < 2; ++r){
    int i = wv + 4*r, h = h0 + i;
    float2 a = unpackh2(zs[i][lane]);
    float2 bb = unpackh2(zs[i][lane+64]);
    fft128_inv(a, bb, twi, lane);
    long rb = ((long)c*H_ + h)*W_;
    Z[v0+rb+lane]    = a.x;  Z[v1+rb+lane]    = a.y;
    Z[v0+rb+lane+64] = bb.x; Z[v1+rb+lane+64] = bb.y;
  }
}

extern "C" void kernel_launch(void* const* d_in, const int* in_sizes, int n_in,
                              void* d_out, int out_size, void* d_ws, size_t ws_size,
                              hipStream_t stream)
{
  const float* Y   = (const float*)d_in[0];
  const float* inW = (const float*)d_in[1];
  float* Z = (float*)d_out;

  // LUT region (8 KB) then fields
  float2* twf_lut = (float2*)d_ws;                 // 7*64 float2
  float2* twi_lut = twf_lut + 7*64;
  float*  dtab    = (float*)(twi_lut + 7*64);      // 128 floats
  char*   fields  = (char*)d_ws + 8192;

  const int HT = TOTAL/2;
  uint2*   YWp = (uint2*)fields;
  __half2* G1  = (__half2*)(YWp + HT);
  __half2* Vh0 = G1  + HT;
  __half2* Vv0 = Vh0 + HT;
  __half2* Vs0 = Vv0 + HT;
  __half2* Vh1 = Vs0 + HT;
  __half2* Vv1 = Vh1 + HT;
  __half2* Vs1 = Vv1 + HT;
  __half2* A0  = Vs1 + HT;
  __half2* A1  = A0  + HT;
  __half2* Vh[2] = {Vh0, Vh1};
  __half2* Vv[2] = {Vv0, Vv1};
  __half2* Vs[2] = {Vs0, Vs1};
  __half2* Ab[2] = {A0, A1};

  kern_init<<<dim3(1), dim3(128), 0, stream>>>(twf_lut, twi_lut, dtab);
  kern_pack<<<dim3(2*CV_/256), dim3(256), 0, stream>>>(Y, inW, YWp);
  kern_fwd0<<<dim3(2*C_*16), dim3(256), 0, stream>>>(Y, Vh0, Vv0, Vs0, A0, 1.0f, twf_lut);

  float mu = 0.1f;
  for (int t = 0; t < 19; ++t){
    kern_CH<<<dim3(2*W_), dim3(1024), 0, stream>>>(Ab[t&1], twf_lut, twi_lut, dtab);
    float mun = mu * RHO_F;
    kern_CA<<<dim3(2*C_*16), dim3(256), 0, stream>>>(
        Ab[t&1], Ab[(t+1)&1],
        Vh[t&1], Vv[t&1], Vs[t&1],
        Vh[(t+1)&1], Vv[(t+1)&1], Vs[(t+1)&1],
        YWp, G1, mu, 0.1f/mun, 1.0f/mun, (t==0) ? 1 : 0,
        twf_lut, twi_lut);
    mu = mun;
  }
  kern_CH<<<dim3(2*W_), dim3(1024), 0, stream>>>(Ab[1], twf_lut, twi_lut, dtab);
  kern_last<<<dim3(2*C_*16), dim3(256), 0, stream>>>(Ab[1], Z, twi_lut);
}

// Round 8
// 700.633 us; speedup vs baseline: 1.1607x; 1.1198x over previous
//
#include <hip/hip_runtime.h>
#include <hip/hip_fp16.h>
#include <math.h>

#define N_ 4
#define C_ 31
#define H_ 128
#define W_ 128
#define TOTAL (N_*C_*H_*W_)
#define CV_ (C_*H_*W_)
#define PI_F 3.14159265358979f
#define RHO_F 1.05f
#define INV_RHO (1.0f/1.05f)
#define NORM2 (1.0f/16384.0f)    // 1/(128*128)

__device__ __forceinline__ float2 cmul(float2 a, float2 b){
  return make_float2(a.x*b.x - a.y*b.y, a.x*b.y + a.y*b.x);
}
__device__ __forceinline__ float2 shflx(float2 v, int m){
  return make_float2(__shfl_xor(v.x, m, 64), __shfl_xor(v.y, m, 64));
}
__device__ __forceinline__ float shrinkf(float x, float t){
  return copysignf(fmaxf(fabsf(x) - t, 0.0f), x);
}
__device__ __forceinline__ uint packh2(float2 v){
  union{__half2 h2; uint u;} cv; cv.h2 = __floats2half2_rn(v.x, v.y); return cv.u;
}
__device__ __forceinline__ float2 unpackh2(uint u){
  union{uint uu; __half2 h2;} cv; cv.uu = u; return __half22float2(cv.h2);
}
// V recurrence: vnew = shrink((1+1/rho)*D - vold/rho, thr) + (vold - D)/rho
__device__ __forceinline__ float2 vupd(float2 D, float2 vo, float thr){
  const float aa = 1.0f + INV_RHO;
  return make_float2(
    shrinkf(aa*D.x - vo.x*INV_RHO, thr) + (vo.x - D.x)*INV_RHO,
    shrinkf(aa*D.y - vo.y*INV_RHO, thr) + (vo.y - D.y)*INV_RHO);
}
__device__ __forceinline__ void load_tw(const float2* __restrict__ lut, float2* tw, int lane){
  #pragma unroll
  for (int i = 0; i < 7; ++i) tw[i] = lut[i*64 + lane];
}

// Forward DIF FFT-128 over a wave; outputs bit-reversed positions.
__device__ __forceinline__ void fft128_fwd(float2& a, float2& b, const float2* twf, int t){
  float2 u = make_float2(a.x + b.x, a.y + b.y);
  float2 d = make_float2(a.x - b.x, a.y - b.y);
  float2 v = cmul(d, twf[0]);
  #pragma unroll
  for (int i = 1; i < 7; ++i){
    int sp = 64 >> i;
    bool up = (t & sp) != 0;
    float2 pu = shflx(u, sp);
    float2 du = up ? make_float2(pu.x - u.x, pu.y - u.y)
                   : make_float2(u.x + pu.x, u.y + pu.y);
    u = cmul(du, twf[i]);
    float2 pv = shflx(v, sp);
    float2 dv = up ? make_float2(pv.x - v.x, pv.y - v.y)
                   : make_float2(v.x + pv.x, v.y + pv.y);
    v = cmul(dv, twf[i]);
  }
  a = u; b = v;
}

// Inverse DIT FFT-128 (unnormalized): bit-reversed in, natural out.
__device__ __forceinline__ void fft128_inv(float2& a, float2& b, const float2* twi, int t){
  float2 u = a, v = b;
  #pragma unroll
  for (int i = 6; i >= 1; --i){
    int sp = 64 >> i;
    bool up = (t & sp) != 0;
    float2 pu = shflx(u, sp);
    float2 e  = up ? pu : u;
    float2 o  = up ? u  : pu;
    float2 wo = cmul(o, twi[i]);
    u = up ? make_float2(e.x - wo.x, e.y - wo.y)
           : make_float2(e.x + wo.x, e.y + wo.y);
    float2 pv = shflx(v, sp);
    float2 ev = up ? pv : v;
    float2 ov = up ? v  : pv;
    float2 wv = cmul(ov, twi[i]);
    v = up ? make_float2(ev.x - wv.x, ev.y - wv.y)
           : make_float2(ev.x + wv.x, ev.y + wv.y);
  }
  float2 tv = cmul(v, twi[0]);
  a = make_float2(u.x + tv.x, u.y + tv.y);
  b = make_float2(u.x - tv.x, u.y - tv.y);
}

// K-1: one-time twiddle/demo LUT init. 1 block, 128 threads.
__global__ __launch_bounds__(128) void kern_init(float2* __restrict__ twf_lut,
    float2* __restrict__ twi_lut, float* __restrict__ dtab)
{
  int t = threadIdx.x;
  if (t < 64){
    float s, c;
    sincosf(-2.0f*PI_F*(float)t/128.0f, &s, &c);
    twf_lut[t] = make_float2(c, s);
    sincosf(+2.0f*PI_F*(float)t/128.0f, &s, &c);
    twi_lut[t] = make_float2(c, s);
    #pragma unroll
    for (int i = 1; i < 7; ++i){
      int sp = 64 >> i;
      float angf = (t & sp) ? -2.0f*PI_F*(float)(t&(sp-1))/(float)(2*sp) : 0.0f;
      sincosf(angf, &s, &c);
      twf_lut[i*64 + t] = make_float2(c, s);
      float angi = +2.0f*PI_F*(float)(t&(sp-1))/(float)(2*sp);
      sincosf(angi, &s, &c);
      twi_lut[i*64 + t] = make_float2(c, s);
    }
  }
  dtab[t] = 2.0f - 2.0f*cosf(2.0f*PI_F*(float)t/128.0f);
}

// K0: one-time pack: YWp[pair][chw] = (half2(y0,iw0), half2(y1,iw1))
__global__ __launch_bounds__(256) void kern_pack(const float* __restrict__ Y,
    const float* __restrict__ W, uint2* __restrict__ YWp)
{
  int i = blockIdx.x * 256 + threadIdx.x;
  int pair = i / CV_, j = i - pair*CV_;
  long b0 = (long)(2*pair)*CV_ + j, b1 = b0 + CV_;
  union{__half2 h2; uint u;} a, b;
  a.h2 = __floats2half2_rn(Y[b0], W[b0]);
  b.h2 = __floats2half2_rn(Y[b1], W[b1]);
  YWp[i] = make_uint2(a.u, b.u);
}

// K1: first iteration: V0 = shrink(D Y), numer0 (Q0=Y), W-FFT -> A0. Writes V0.
__global__ __launch_bounds__(256) void kern_fwd0(const float* __restrict__ Y,
    __half2* __restrict__ Vho, __half2* __restrict__ Vvo, __half2* __restrict__ Vso,
    __half2* __restrict__ A, float thr, const float2* __restrict__ twf_lut)
{
  __shared__ float2 zbuf[26][128];
  __shared__ uint   zs[25][128];
  int tid = threadIdx.x, lane = tid & 63, wv = tid >> 6;
  int b = blockIdx.x;
  int ht = b & 15, c = (b >> 4) % C_, pair = b / (16*C_);
  int h0 = ht * 8;
  int cm1 = c ? c-1 : C_-1, cp1 = (c == C_-1) ? 0 : c+1;
  long v0 = (long)(2*pair)*CV_, v1 = v0 + CV_;

  for (int u = wv; u < 26; u += 4){
    int cc, h;
    if (u < 10){ cc = c; h = (h0 - 1 + u) & (H_-1); }
    else if (u < 18){ cc = cm1; h = h0 + u - 10; }
    else { cc = cp1; h = h0 + u - 18; }
    long rb = ((long)cc*H_ + h)*W_;
    #pragma unroll
    for (int e = 0; e < 2; ++e){
      int w = lane + 64*e;
      zbuf[u][w] = make_float2(Y[v0+rb+w], Y[v1+rb+w]);
    }
  }
  __syncthreads();

  float2 q[2][2], vs[2][2], vsm[2][2];
  #pragma unroll
  for (int r = 0; r < 2; ++r){
    int i = wv + 4*r, h = h0 + i;
    long pv = ((long)(pair*C_ + c)*H_ + h)*W_;
    #pragma unroll
    for (int e = 0; e < 2; ++e){
      int w = lane + 64*e;
      float2 z0 = zbuf[i+1][w];
      float2 zw = zbuf[i+1][(w+1)&(W_-1)];
      float2 zh = zbuf[i+2][w];
      float2 zc = zbuf[18+i][w];
      float2 zm = zbuf[10+i][w];
      float2 vh = make_float2(shrinkf(z0.x-zw.x,thr), shrinkf(z0.y-zw.y,thr));
      float2 vv = make_float2(shrinkf(z0.x-zh.x,thr), shrinkf(z0.y-zh.y,thr));
      float2 vsl= make_float2(shrinkf(z0.x-zc.x,thr), shrinkf(z0.y-zc.y,thr));
      vsm[r][e] = make_float2(shrinkf(zm.x-z0.x,thr), shrinkf(zm.y-z0.y,thr));
      Vho[pv+w] = __floats2half2_rn(vh.x, vh.y);
      Vvo[pv+w] = __floats2half2_rn(vv.x, vv.y);
      Vso[pv+w] = __floats2half2_rn(vsl.x, vsl.y);
      zs[i][w]   = packh2(vh);
      zs[9+i][w] = packh2(vv);
      vs[r][e] = vsl;
      q[r][e]  = z0;
    }
  }
  if (wv == 0){
    #pragma unroll
    for (int e = 0; e < 2; ++e){
      int w = lane + 64*e;
      float2 z0 = zbuf[0][w], zh = zbuf[1][w];
      float2 vvm = make_float2(shrinkf(z0.x-zh.x,thr), shrinkf(z0.y-zh.y,thr));
      zs[8][w] = packh2(vvm);
    }
  }
  __syncthreads();

  float2 twf[7]; load_tw(twf_lut, twf, lane);
  #pragma unroll
  for (int r = 0; r < 2; ++r){
    int i = wv + 4*r;
    float2 nm[2];
    #pragma unroll
    for (int e = 0; e < 2; ++e){
      int w = lane + 64*e;
      float2 vh  = unpackh2(zs[i][w]);
      float2 vhm = unpackh2(zs[i][(w+W_-1)&(W_-1)]);
      float2 vv  = unpackh2(zs[9+i][w]);
      float2 vvm = unpackh2(zs[8+i][w]);
      nm[e] = make_float2(q[r][e].x + (vh.x-vhm.x) + (vv.x-vvm.x) + (vs[r][e].x - vsm[r][e].x),
                          q[r][e].y + (vh.y-vhm.y) + (vv.y-vvm.y) + (vs[r][e].y - vsm[r][e].y));
    }
    fft128_fwd(nm[0], nm[1], twf, lane);
    zs[17+i][lane]    = packh2(nm[0]);
    zs[17+i][lane+64] = packh2(nm[1]);
  }
  __syncthreads();
  int4* A4 = (int4*)A;
  int p = tid >> 1, hq = tid & 1;
  union{int4 v; uint e[4];} u;
  #pragma unroll
  for (int j = 0; j < 4; ++j) u.e[j] = zs[17 + 4*hq + j][p];
  A4[((long)(pair*W_ + p)*C_ + c)*32 + 2*ht + hq] = u.v;
}

// K2: H-FFT fwd + 25-tap circulant c-solve + H-FFT inv, per (pair, w) slab. In place.
// Dual-row FFT per wave: 2 independent butterfly chains (ILP 4).
__global__ __launch_bounds__(1024) void kern_CH(__half2* __restrict__ A,
    const float2* __restrict__ twf_lut, const float2* __restrict__ twi_lut,
    const float* __restrict__ dtab)
{
  __shared__ float2 slab[C_][H_];
  int tid = threadIdx.x, lane = tid & 63, wv = tid >> 6;
  int bid = blockIdx.x;                 // pair*128 + w
  int w = bid & (W_-1);
  const int4* g4 = (const int4*)(A + (long)bid * C_ * H_);

  if (tid < 992){
    union { int4 v; __half2 e[4]; } u;
    u.v = g4[tid];
    int c = tid >> 5, hb = (tid & 31) << 2;
    #pragma unroll
    for (int j = 0; j < 4; ++j) slab[c][hb+j] = __half22float2(u.e[j]);
  }
  float2 twf[7];
  load_tw(twf_lut, twf, lane);
  __syncthreads();

  // H-FFT forward: wave wv owns rows wv and wv+16 (second guarded; clamp read)
  {
    int c1 = wv, c2 = (wv + 16 < C_) ? wv + 16 : (C_-1);
    float2 a0 = slab[c1][lane], b0 = slab[c1][lane+64];
    float2 a1 = slab[c2][lane], b1 = slab[c2][lane+64];
    fft128_fwd(a0, b0, twf, lane);
    fft128_fwd(a1, b1, twf, lane);
    slab[c1][lane] = a0; slab[c1][lane+64] = b0;
    if (wv + 16 < C_){ slab[c2][lane] = a1; slab[c2][lane+64] = b1; }
  }
  __syncthreads();

  {
    int col = tid & (H_-1), cb = tid >> 7, c0 = cb * 4;
    int fh = __brev(col) >> 25;
    int fw = __brev(w)   >> 25;
    float beta = 1.0f + dtab[fh] + dtab[fw];
    float a2 = beta + 2.0f;
    float s  = sqrtf(a2*a2 - 4.0f);
    float rg = (a2 - s) * 0.5f;
    float gt[13];
    gt[0] = NORM2 / s;
    #pragma unroll
    for (int t = 1; t < 13; ++t) gt[t] = gt[t-1] * rg;

    float2 win[28];
    #pragma unroll
    for (int i = 0; i < 28; ++i){
      int ci = c0 - 12 + i;
      if (ci < 0) ci += C_;
      if (ci >= C_) ci -= C_;
      win[i] = slab[ci][col];
    }
    float2 out[4];
    #pragma unroll
    for (int j = 0; j < 4; ++j){
      float ox = 0.0f, oy = 0.0f;
      #pragma unroll
      for (int t = -12; t <= 12; ++t){
        float gv = gt[t < 0 ? -t : t];
        float2 xv = win[j + 12 - t];
        ox += gv * xv.x;
        oy += gv * xv.y;
      }
      out[j] = make_float2(ox, oy);
    }
    __syncthreads();
    #pragma unroll
    for (int j = 0; j < 4; ++j){
      int c = c0 + j;
      if (c < C_) slab[c][col] = out[j];
    }
  }
  __syncthreads();

  // H-FFT inverse: dual-row per wave
  {
    float2 twi[7];
    load_tw(twi_lut, twi, lane);
    int c1 = wv, c2 = (wv + 16 < C_) ? wv + 16 : (C_-1);
    float2 a0 = slab[c1][lane], b0 = slab[c1][lane+64];
    float2 a1 = slab[c2][lane], b1 = slab[c2][lane+64];
    fft128_inv(a0, b0, twi, lane);
    fft128_inv(a1, b1, twi, lane);
    slab[c1][lane] = a0; slab[c1][lane+64] = b0;
    if (wv + 16 < C_){ slab[c2][lane] = a1; slab[c2][lane+64] = b1; }
  }
  __syncthreads();
  int4* go4 = (int4*)(A + (long)bid * C_ * H_);
  if (tid < 992){
    int c = tid >> 5, hb = (tid & 31) << 2;
    union { int4 v; __half2 e[4]; } u;
    #pragma unroll
    for (int j = 0; j < 4; ++j){
      float2 f = slab[c][hb+j];
      u.e[j] = __floats2half2_rn(f.x, f.y);
    }
    go4[tid] = u.v;
  }
}

// K3: fused iteration tail+head (512 threads = 8 waves):
// prefetch state -> stage A -> iW-FFT 26 rows (4/wave, batched) -> V/X/G1/Q -> numer -> W-FFT -> A_{t+1}.
__global__ __launch_bounds__(512) void kern_CA(
    const __half2* __restrict__ Ain, __half2* __restrict__ Aout,
    const __half2* __restrict__ Vhi, const __half2* __restrict__ Vvi, const __half2* __restrict__ Vsi,
    __half2* __restrict__ Vho, __half2* __restrict__ Vvo, __half2* __restrict__ Vso,
    const uint2* __restrict__ YWp, __half2* __restrict__ G1,
    float mu, float thrn, float invmun, int firstG,
    const float2* __restrict__ twf_lut, const float2* __restrict__ twi_lut)
{
  __shared__ float2 zbuf[26][128];
  __shared__ uint   zs[32][128];
  int tid = threadIdx.x, lane = tid & 63, wv = tid >> 6;   // wv 0..7
  int b = blockIdx.x;
  int ht = b & 15, c = (b >> 4) % C_, pair = b / (16*C_);
  int h0 = ht * 8;
  int cm1 = c ? c-1 : C_-1, cp1 = (c == C_-1) ? 0 : c+1;

  // prefetch own-row global state; latency hides under phases 0-1
  int hrow = h0 + wv;
  long pv  = ((long)(pair*C_ + c  )*H_ + hrow)*W_;
  long pvm = ((long)(pair*C_ + cm1)*H_ + hrow)*W_;
  uint pf_vh[2], pf_vv[2], pf_vs[2], pf_vsm[2], pf_g1[2], pf_vvh[2];
  uint2 pf_yw[2];
  #pragma unroll
  for (int e = 0; e < 2; ++e){
    int w = lane + 64*e;
    pf_vh[e]  = *(const uint*)(Vhi + pv + w);
    pf_vv[e]  = *(const uint*)(Vvi + pv + w);
    pf_vs[e]  = *(const uint*)(Vsi + pv + w);
    pf_vsm[e] = *(const uint*)(Vsi + pvm + w);
    pf_yw[e]  = YWp[pv + w];
    pf_g1[e]  = *(const uint*)(G1 + pv + w);
  }
  if (wv == 0){
    long pvh = ((long)(pair*C_ + c)*H_ + ((h0+H_-1)&(H_-1)))*W_;
    #pragma unroll
    for (int e = 0; e < 2; ++e){
      int w = lane + 64*e;
      pf_vvh[e] = *(const uint*)(Vvi + pvh + w);
    }
  }

  // phase 0: stage A (fp16 spectra) with halos
  const int4* A4 = (const int4*)Ain;
  #pragma unroll
  for (int k = 0; k < 2; ++k){
    int i = tid + 512*k;               // 0..1023
    int w = i & 127;
    int quad, cc, dr;
    if (i < 512){ int qi = i >> 7; quad = (2*ht - 1 + qi) & 31; cc = c;   dr = 4*qi; }
    else if (i < 768){ int qi = (i >> 7) & 1; quad = 2*ht + qi; cc = cm1; dr = 16 + 4*qi; }
    else { int qi = (i >> 7) & 1; quad = 2*ht + qi; cc = cp1; dr = 24 + 4*qi; }
    union{int4 v; uint e[4];} u;
    u.v = A4[((long)(pair*W_ + w)*C_ + cc)*32 + quad];
    #pragma unroll
    for (int j = 0; j < 4; ++j) zs[dr+j][w] = u.e[j];
  }
  __syncthreads();

  // phase 1: inverse W-FFT of 26 rows, 4 per wave in one batch (ILP 8)
  {
    float2 twi[7]; load_tw(twi_lut, twi, lane);
    float2 ra[4], rb[4];
    #pragma unroll
    for (int k = 0; k < 4; ++k){
      int uu = wv + 8*k; if (uu > 25) uu = 25;
      int zr = (uu < 10) ? (uu + 3) : (uu + 6);
      ra[k] = unpackh2(zs[zr][lane]);
      rb[k] = unpackh2(zs[zr][lane+64]);
    }
    #pragma unroll
    for (int k = 0; k < 4; ++k) fft128_inv(ra[k], rb[k], twi, lane);
    #pragma unroll
    for (int k = 0; k < 4; ++k){
      int uu = wv + 8*k;
      if (uu < 26){ zbuf[uu][lane] = ra[k]; zbuf[uu][lane+64] = rb[k]; }
    }
  }
  __syncthreads();

  // phase 2a: V_{t+1} (own row), X/G1/Q — uses prefetched state
  float2 q[2], vs[2], vsm[2];
  {
    int i = wv;
    #pragma unroll
    for (int e = 0; e < 2; ++e){
      int w = lane + 64*e;
      float2 z0 = zbuf[i+1][w];
      float2 zw = zbuf[i+1][(w+1)&(W_-1)];
      float2 zh = zbuf[i+2][w];
      float2 zc = zbuf[18+i][w];
      float2 zm = zbuf[10+i][w];
      float2 vh  = vupd(make_float2(z0.x-zw.x, z0.y-zw.y), unpackh2(pf_vh[e]), thrn);
      float2 vv  = vupd(make_float2(z0.x-zh.x, z0.y-zh.y), unpackh2(pf_vv[e]), thrn);
      float2 vsl = vupd(make_float2(z0.x-zc.x, z0.y-zc.y), unpackh2(pf_vs[e]), thrn);
      vsm[e]     = vupd(make_float2(zm.x-z0.x, zm.y-z0.y), unpackh2(pf_vsm[e]), thrn);
      Vho[pv+w] = __floats2half2_rn(vh.x, vh.y);
      Vvo[pv+w] = __floats2half2_rn(vv.x, vv.y);
      Vso[pv+w] = __floats2half2_rn(vsl.x, vsl.y);
      zs[i][w]   = packh2(vh);
      zs[9+i][w] = packh2(vv);
      vs[e] = vsl;
      float2 a0 = unpackh2(pf_yw[e].x);   // (y, iw) vol0
      float2 a1 = unpackh2(pf_yw[e].y);   // (y, iw) vol1
      float2 g1 = firstG ? make_float2(0.0f, 0.0f) : unpackh2(pf_g1[e]);
      float x0 = (a0.y*a0.x + mu*z0.x - g1.x) / (a0.y + mu);
      float x1 = (a1.y*a1.x + mu*z0.y - g1.y) / (a1.y + mu);
      float g10 = g1.x + mu*(x0 - z0.x);
      float g11 = g1.y + mu*(x1 - z0.y);
      G1[pv+w] = __floats2half2_rn(g10, g11);
      q[e] = make_float2(x0 + g10*invmun, x1 + g11*invmun);
    }
  }
  if (wv == 0){
    #pragma unroll
    for (int e = 0; e < 2; ++e){
      int w = lane + 64*e;
      float2 z0 = zbuf[0][w], zh = zbuf[1][w];
      float2 vvm = vupd(make_float2(z0.x-zh.x, z0.y-zh.y), unpackh2(pf_vvh[e]), thrn);
      zs[8][w] = packh2(vvm);
    }
  }
  __syncthreads();

  // phase 2b: numer + forward W-FFT -> tbuf
  {
    float2 twf[7]; load_tw(twf_lut, twf, lane);
    int i = wv;
    float2 nm[2];
    #pragma unroll
    for (int e = 0; e < 2; ++e){
      int w = lane + 64*e;
      float2 vh  = unpackh2(zs[i][w]);
      float2 vhm = unpackh2(zs[i][(w+W_-1)&(W_-1)]);
      float2 vv  = unpackh2(zs[9+i][w]);
      float2 vvm = unpackh2(zs[8+i][w]);
      nm[e] = make_float2(q[e].x + (vh.x-vhm.x) + (vv.x-vvm.x) + (vs[e].x - vsm[e].x),
                          q[e].y + (vh.y-vhm.y) + (vv.y-vvm.y) + (vs[e].y - vsm[e].y));
    }
    fft128_fwd(nm[0], nm[1], twf, lane);
    zs[17+i][lane]    = packh2(nm[0]);
    zs[17+i][lane+64] = packh2(nm[1]);
  }
  __syncthreads();
  if (tid < 256){
    int4* Ao4 = (int4*)Aout;
    int p = tid >> 1, hq = tid & 1;
    union{int4 v; uint e[4];} uo;
    #pragma unroll
    for (int j = 0; j < 4; ++j) uo.e[j] = zs[17 + 4*hq + j][p];
    Ao4[((long)(pair*W_ + p)*C_ + c)*32 + 2*ht + hq] = uo.v;
  }
}

// K4: final: iW-FFT own rows only -> Z fp32.
__global__ __launch_bounds__(256) void kern_last(const __half2* __restrict__ A,
    float* __restrict__ Z, const float2* __restrict__ twi_lut)
{
  __shared__ uint zs[8][128];
  int tid = threadIdx.x, lane = tid & 63, wv = tid >> 6;
  int b = blockIdx.x;
  int ht = b & 15, c = (b >> 4) % C_, pair = b / (16*C_);
  int h0 = ht * 8;
  const int4* A4 = (const int4*)A;
  {
    int p = tid >> 1, hq = tid & 1;
    union{int4 v; uint e[4];} u;
    u.v = A4[((long)(pair*W_ + p)*C_ + c)*32 + 2*ht + hq];
    #pragma unroll
    for (int j = 0; j < 4; ++j) zs[4*hq + j][p] = u.e[j];
  }
  __syncthreads();
  float2 twi[7]; load_tw(twi_lut, twi, lane);
  long v0 = (long)(2*pair)*CV_, v1 = v0 + CV_;
  #pragma unroll
  for (int r = 0; r < 2; ++r){
    int i = wv + 4*r, h = h0 + i;
    float2 a = unpackh2(zs[i][lane]);
    float2 bb = unpackh2(zs[i][lane+64]);
    fft128_inv(a, bb, twi, lane);
    long rb = ((long)c*H_ + h)*W_;
    Z[v0+rb+lane]    = a.x;  Z[v1+rb+lane]    = a.y;
    Z[v0+rb+lane+64] = bb.x; Z[v1+rb+lane+64] = bb.y;
  }
}

extern "C" void kernel_launch(void* const* d_in, const int* in_sizes, int n_in,
                              void* d_out, int out_size, void* d_ws, size_t ws_size,
                              hipStream_t stream)
{
  const float* Y   = (const float*)d_in[0];
  const float* inW = (const float*)d_in[1];
  float* Z = (float*)d_out;

  float2* twf_lut = (float2*)d_ws;
  float2* twi_lut = twf_lut + 7*64;
  float*  dtab    = (float*)(twi_lut + 7*64);
  char*   fields  = (char*)d_ws + 8192;

  const int HT = TOTAL/2;
  uint2*   YWp = (uint2*)fields;
  __half2* G1  = (__half2*)(YWp + HT);
  __half2* Vh0 = G1  + HT;
  __half2* Vv0 = Vh0 + HT;
  __half2* Vs0 = Vv0 + HT;
  __half2* Vh1 = Vs0 + HT;
  __half2* Vv1 = Vh1 + HT;
  __half2* Vs1 = Vv1 + HT;
  __half2* A0  = Vs1 + HT;
  __half2* A1  = A0  + HT;
  __half2* Vh[2] = {Vh0, Vh1};
  __half2* Vv[2] = {Vv0, Vv1};
  __half2* Vs[2] = {Vs0, Vs1};
  __half2* Ab[2] = {A0, A1};

  kern_init<<<dim3(1), dim3(128), 0, stream>>>(twf_lut, twi_lut, dtab);
  kern_pack<<<dim3(2*CV_/256), dim3(256), 0, stream>>>(Y, inW, YWp);
  kern_fwd0<<<dim3(2*C_*16), dim3(256), 0, stream>>>(Y, Vh0, Vv0, Vs0, A0, 1.0f, twf_lut);

  float mu = 0.1f;
  for (int t = 0; t < 19; ++t){
    kern_CH<<<dim3(2*W_), dim3(1024), 0, stream>>>(Ab[t&1], twf_lut, twi_lut, dtab);
    float mun = mu * RHO_F;
    kern_CA<<<dim3(2*C_*16), dim3(512), 0, stream>>>(
        Ab[t&1], Ab[(t+1)&1],
        Vh[t&1], Vv[t&1], Vs[t&1],
        Vh[(t+1)&1], Vv[(t+1)&1], Vs[(t+1)&1],
        YWp, G1, mu, 0.1f/mun, 1.0f/mun, (t==0) ? 1 : 0,
        twf_lut, twi_lut);
    mu = mun;
  }
  kern_CH<<<dim3(2*W_), dim3(1024), 0, stream>>>(Ab[1], twf_lut, twi_lut, dtab);
  kern_last<<<dim3(2*C_*16), dim3(256), 0, stream>>>(Ab[1], Z, twi_lut);
}

// Round 9
// 660.636 us; speedup vs baseline: 1.2310x; 1.0605x over previous
//
#include <hip/hip_runtime.h>
#include <hip/hip_fp16.h>
#include <math.h>

#define N_ 4
#define C_ 31
#define H_ 128
#define W_ 128
#define TOTAL (N_*C_*H_*W_)
#define CV_ (C_*H_*W_)
#define PI_F 3.14159265358979f
#define RHO_F 1.05f
#define INV_RHO (1.0f/1.05f)
#define NORM2 (1.0f/16384.0f)    // 1/(128*128)

__device__ __forceinline__ float2 cmul(float2 a, float2 b){
  return make_float2(a.x*b.x - a.y*b.y, a.x*b.y + a.y*b.x);
}
__device__ __forceinline__ float2 shflx(float2 v, int m){
  return make_float2(__shfl_xor(v.x, m, 64), __shfl_xor(v.y, m, 64));
}
__device__ __forceinline__ float shrinkf(float x, float t){
  return copysignf(fmaxf(fabsf(x) - t, 0.0f), x);
}
__device__ __forceinline__ uint packh2(float2 v){
  union{__half2 h2; uint u;} cv; cv.h2 = __floats2half2_rn(v.x, v.y); return cv.u;
}
__device__ __forceinline__ float2 unpackh2(uint u){
  union{uint uu; __half2 h2;} cv; cv.uu = u; return __half22float2(cv.h2);
}
// V recurrence: vnew = shrink((1+1/rho)*D - vold/rho, thr) + (vold - D)/rho
__device__ __forceinline__ float2 vupd(float2 D, float2 vo, float thr){
  const float aa = 1.0f + INV_RHO;
  return make_float2(
    shrinkf(aa*D.x - vo.x*INV_RHO, thr) + (vo.x - D.x)*INV_RHO,
    shrinkf(aa*D.y - vo.y*INV_RHO, thr) + (vo.y - D.y)*INV_RHO);
}
__device__ __forceinline__ void load_tw(const float2* __restrict__ lut, float2* tw, int lane){
  #pragma unroll
  for (int i = 0; i < 7; ++i) tw[i] = lut[i*64 + lane];
}

// Forward DIF FFT-128 over a wave; outputs bit-reversed positions.
__device__ __forceinline__ void fft128_fwd(float2& a, float2& b, const float2* twf, int t){
  float2 u = make_float2(a.x + b.x, a.y + b.y);
  float2 d = make_float2(a.x - b.x, a.y - b.y);
  float2 v = cmul(d, twf[0]);
  #pragma unroll
  for (int i = 1; i < 7; ++i){
    int sp = 64 >> i;
    bool up = (t & sp) != 0;
    float2 pu = shflx(u, sp);
    float2 du = up ? make_float2(pu.x - u.x, pu.y - u.y)
                   : make_float2(u.x + pu.x, u.y + pu.y);
    u = cmul(du, twf[i]);
    float2 pv = shflx(v, sp);
    float2 dv = up ? make_float2(pv.x - v.x, pv.y - v.y)
                   : make_float2(v.x + pv.x, v.y + pv.y);
    v = cmul(dv, twf[i]);
  }
  a = u; b = v;
}

// Inverse DIT FFT-128 (unnormalized): bit-reversed in, natural out.
__device__ __forceinline__ void fft128_inv(float2& a, float2& b, const float2* twi, int t){
  float2 u = a, v = b;
  #pragma unroll
  for (int i = 6; i >= 1; --i){
    int sp = 64 >> i;
    bool up = (t & sp) != 0;
    float2 pu = shflx(u, sp);
    float2 e  = up ? pu : u;
    float2 o  = up ? u  : pu;
    float2 wo = cmul(o, twi[i]);
    u = up ? make_float2(e.x - wo.x, e.y - wo.y)
           : make_float2(e.x + wo.x, e.y + wo.y);
    float2 pv = shflx(v, sp);
    float2 ev = up ? pv : v;
    float2 ov = up ? v  : pv;
    float2 wv = cmul(ov, twi[i]);
    v = up ? make_float2(ev.x - wv.x, ev.y - wv.y)
           : make_float2(ev.x + wv.x, ev.y + wv.y);
  }
  float2 tv = cmul(v, twi[0]);
  a = make_float2(u.x + tv.x, u.y + tv.y);
  b = make_float2(u.x - tv.x, u.y - tv.y);
}

// K-1: one-time twiddle/demo LUT init. 1 block, 128 threads.
__global__ __launch_bounds__(128) void kern_init(float2* __restrict__ twf_lut,
    float2* __restrict__ twi_lut, float* __restrict__ dtab)
{
  int t = threadIdx.x;
  if (t < 64){
    float s, c;
    sincosf(-2.0f*PI_F*(float)t/128.0f, &s, &c);
    twf_lut[t] = make_float2(c, s);
    sincosf(+2.0f*PI_F*(float)t/128.0f, &s, &c);
    twi_lut[t] = make_float2(c, s);
    #pragma unroll
    for (int i = 1; i < 7; ++i){
      int sp = 64 >> i;
      float angf = (t & sp) ? -2.0f*PI_F*(float)(t&(sp-1))/(float)(2*sp) : 0.0f;
      sincosf(angf, &s, &c);
      twf_lut[i*64 + t] = make_float2(c, s);
      float angi = +2.0f*PI_F*(float)(t&(sp-1))/(float)(2*sp);
      sincosf(angi, &s, &c);
      twi_lut[i*64 + t] = make_float2(c, s);
    }
  }
  dtab[t] = 2.0f - 2.0f*cosf(2.0f*PI_F*(float)t/128.0f);
}

// K0: one-time pack: YWp[pair][chw] = (half2(y0,iw0), half2(y1,iw1))
__global__ __launch_bounds__(256) void kern_pack(const float* __restrict__ Y,
    const float* __restrict__ W, uint2* __restrict__ YWp)
{
  int i = blockIdx.x * 256 + threadIdx.x;
  int pair = i / CV_, j = i - pair*CV_;
  long b0 = (long)(2*pair)*CV_ + j, b1 = b0 + CV_;
  union{__half2 h2; uint u;} a, b;
  a.h2 = __floats2half2_rn(Y[b0], W[b0]);
  b.h2 = __floats2half2_rn(Y[b1], W[b1]);
  YWp[i] = make_uint2(a.u, b.u);
}

// K1: first iteration: V0 = shrink(D Y), numer0 (Q0=Y), W-FFT -> A0. Writes V0.
// Old 1c x 8h tiling, grid 2*C*16, 256 thr. One-shot kernel.
__global__ __launch_bounds__(256) void kern_fwd0(const float* __restrict__ Y,
    __half2* __restrict__ Vho, __half2* __restrict__ Vvo, __half2* __restrict__ Vso,
    __half2* __restrict__ A, float thr, const float2* __restrict__ twf_lut)
{
  __shared__ float2 zbuf[26][128];
  __shared__ uint   zs[25][128];
  int tid = threadIdx.x, lane = tid & 63, wv = tid >> 6;
  int b = blockIdx.x;
  int ht = b & 15, c = (b >> 4) % C_, pair = b / (16*C_);
  int h0 = ht * 8;
  int cm1 = c ? c-1 : C_-1, cp1 = (c == C_-1) ? 0 : c+1;
  long v0 = (long)(2*pair)*CV_, v1 = v0 + CV_;

  for (int u = wv; u < 26; u += 4){
    int cc, h;
    if (u < 10){ cc = c; h = (h0 - 1 + u) & (H_-1); }
    else if (u < 18){ cc = cm1; h = h0 + u - 10; }
    else { cc = cp1; h = h0 + u - 18; }
    long rb = ((long)cc*H_ + h)*W_;
    #pragma unroll
    for (int e = 0; e < 2; ++e){
      int w = lane + 64*e;
      zbuf[u][w] = make_float2(Y[v0+rb+w], Y[v1+rb+w]);
    }
  }
  __syncthreads();

  float2 q[2][2], vs[2][2], vsm[2][2];
  #pragma unroll
  for (int r = 0; r < 2; ++r){
    int i = wv + 4*r, h = h0 + i;
    long pv = ((long)(pair*C_ + c)*H_ + h)*W_;
    #pragma unroll
    for (int e = 0; e < 2; ++e){
      int w = lane + 64*e;
      float2 z0 = zbuf[i+1][w];
      float2 zw = zbuf[i+1][(w+1)&(W_-1)];
      float2 zh = zbuf[i+2][w];
      float2 zc = zbuf[18+i][w];
      float2 zm = zbuf[10+i][w];
      float2 vh = make_float2(shrinkf(z0.x-zw.x,thr), shrinkf(z0.y-zw.y,thr));
      float2 vv = make_float2(shrinkf(z0.x-zh.x,thr), shrinkf(z0.y-zh.y,thr));
      float2 vsl= make_float2(shrinkf(z0.x-zc.x,thr), shrinkf(z0.y-zc.y,thr));
      vsm[r][e] = make_float2(shrinkf(zm.x-z0.x,thr), shrinkf(zm.y-z0.y,thr));
      Vho[pv+w] = __floats2half2_rn(vh.x, vh.y);
      Vvo[pv+w] = __floats2half2_rn(vv.x, vv.y);
      Vso[pv+w] = __floats2half2_rn(vsl.x, vsl.y);
      zs[i][w]   = packh2(vh);
      zs[9+i][w] = packh2(vv);
      vs[r][e] = vsl;
      q[r][e]  = z0;
    }
  }
  if (wv == 0){
    #pragma unroll
    for (int e = 0; e < 2; ++e){
      int w = lane + 64*e;
      float2 z0 = zbuf[0][w], zh = zbuf[1][w];
      float2 vvm = make_float2(shrinkf(z0.x-zh.x,thr), shrinkf(z0.y-zh.y,thr));
      zs[8][w] = packh2(vvm);
    }
  }
  __syncthreads();

  float2 twf[7]; load_tw(twf_lut, twf, lane);
  #pragma unroll
  for (int r = 0; r < 2; ++r){
    int i = wv + 4*r;
    float2 nm[2];
    #pragma unroll
    for (int e = 0; e < 2; ++e){
      int w = lane + 64*e;
      float2 vh  = unpackh2(zs[i][w]);
      float2 vhm = unpackh2(zs[i][(w+W_-1)&(W_-1)]);
      float2 vv  = unpackh2(zs[9+i][w]);
      float2 vvm = unpackh2(zs[8+i][w]);
      nm[e] = make_float2(q[r][e].x + (vh.x-vhm.x) + (vv.x-vvm.x) + (vs[r][e].x - vsm[r][e].x),
                          q[r][e].y + (vh.y-vhm.y) + (vv.y-vvm.y) + (vs[r][e].y - vsm[r][e].y));
    }
    fft128_fwd(nm[0], nm[1], twf, lane);
    zs[17+i][lane]    = packh2(nm[0]);
    zs[17+i][lane+64] = packh2(nm[1]);
  }
  __syncthreads();
  int4* A4 = (int4*)A;
  int p = tid >> 1, hq = tid & 1;
  union{int4 v; uint e[4];} u;
  #pragma unroll
  for (int j = 0; j < 4; ++j) u.e[j] = zs[17 + 4*hq + j][p];
  A4[((long)(pair*W_ + p)*C_ + c)*32 + 2*ht + hq] = u.v;
}

// K2: H-FFT fwd + 17-tap circulant c-solve + H-FFT inv, per (pair, w) slab. In place.
// Dual-row FFT per wave (ILP 4); conv writes to second slab (one fewer barrier).
__global__ __launch_bounds__(1024) void kern_CH(__half2* __restrict__ A,
    const float2* __restrict__ twf_lut, const float2* __restrict__ twi_lut,
    const float* __restrict__ dtab)
{
  __shared__ float2 slab[C_][H_];
  __shared__ float2 slab2[C_][H_];
  int tid = threadIdx.x, lane = tid & 63, wv = tid >> 6;
  int bid = blockIdx.x;                 // pair*128 + w
  int w = bid & (W_-1);
  const int4* g4 = (const int4*)(A + (long)bid * C_ * H_);

  if (tid < 992){
    union { int4 v; __half2 e[4]; } u;
    u.v = g4[tid];
    int c = tid >> 5, hb = (tid & 31) << 2;
    #pragma unroll
    for (int j = 0; j < 4; ++j) slab[c][hb+j] = __half22float2(u.e[j]);
  }
  float2 twf[7];
  load_tw(twf_lut, twf, lane);
  __syncthreads();

  // H-FFT forward: wave wv owns rows wv and wv+16
  {
    int c1 = wv, c2 = (wv + 16 < C_) ? wv + 16 : (C_-1);
    float2 a0 = slab[c1][lane], b0 = slab[c1][lane+64];
    float2 a1 = slab[c2][lane], b1 = slab[c2][lane+64];
    fft128_fwd(a0, b0, twf, lane);
    fft128_fwd(a1, b1, twf, lane);
    slab[c1][lane] = a0; slab[c1][lane+64] = b0;
    if (wv + 16 < C_){ slab[c2][lane] = a1; slab[c2][lane+64] = b1; }
  }
  __syncthreads();

  // 17-tap circulant conv along c: thread = (h-col, 4-c-block); slab -> slab2
  {
    int col = tid & (H_-1), cb = tid >> 7, c0 = cb * 4;
    int fh = __brev(col) >> 25;
    int fw = __brev(w)   >> 25;
    float beta = 1.0f + dtab[fh] + dtab[fw];
    float a2 = beta + 2.0f;
    float s  = sqrtf(a2*a2 - 4.0f);
    float rg = (a2 - s) * 0.5f;
    float gt[9];
    gt[0] = NORM2 / s;
    #pragma unroll
    for (int t = 1; t < 9; ++t) gt[t] = gt[t-1] * rg;

    float2 win[20];
    #pragma unroll
    for (int i = 0; i < 20; ++i){
      int ci = c0 - 8 + i;
      if (ci < 0) ci += C_;
      if (ci >= C_) ci -= C_;
      win[i] = slab[ci][col];
    }
    #pragma unroll
    for (int j = 0; j < 4; ++j){
      float ox = 0.0f, oy = 0.0f;
      #pragma unroll
      for (int t = -8; t <= 8; ++t){
        float gv = gt[t < 0 ? -t : t];
        float2 xv = win[j + 8 - t];
        ox += gv * xv.x;
        oy += gv * xv.y;
      }
      int c = c0 + j;
      if (c < C_) slab2[c][col] = make_float2(ox, oy);
    }
  }
  __syncthreads();

  // H-FFT inverse (slab2 in place): dual-row per wave
  {
    float2 twi[7];
    load_tw(twi_lut, twi, lane);
    int c1 = wv, c2 = (wv + 16 < C_) ? wv + 16 : (C_-1);
    float2 a0 = slab2[c1][lane], b0 = slab2[c1][lane+64];
    float2 a1 = slab2[c2][lane], b1 = slab2[c2][lane+64];
    fft128_inv(a0, b0, twi, lane);
    fft128_inv(a1, b1, twi, lane);
    slab2[c1][lane] = a0; slab2[c1][lane+64] = b0;
    if (wv + 16 < C_){ slab2[c2][lane] = a1; slab2[c2][lane+64] = b1; }
  }
  __syncthreads();
  int4* go4 = (int4*)(A + (long)bid * C_ * H_);
  if (tid < 992){
    int c = tid >> 5, hb = (tid & 31) << 2;
    union { int4 v; __half2 e[4]; } u;
    #pragma unroll
    for (int j = 0; j < 4; ++j){
      float2 f = slab2[c][hb+j];
      u.e[j] = __floats2half2_rn(f.x, f.y);
    }
    go4[tid] = u.v;
  }
}

// K3: fused iteration tail+head, 2-c x 8-h tiles (512 thr = 8 waves).
// grid = 2 pairs * 16 ctiles * 16 htiles = 512. ctile 15 has nc=1 (c=30).
__global__ __launch_bounds__(512,4) void kern_CA(
    const __half2* __restrict__ Ain, __half2* __restrict__ Aout,
    const __half2* __restrict__ Vhi, const __half2* __restrict__ Vvi, const __half2* __restrict__ Vsi,
    __half2* __restrict__ Vho, __half2* __restrict__ Vvo, __half2* __restrict__ Vso,
    const uint2* __restrict__ YWp, __half2* __restrict__ G1,
    float mu, float thrn, float invmun, int firstG,
    const float2* __restrict__ twf_lut, const float2* __restrict__ twi_lut)
{
  __shared__ float2 zbuf[36][128];
  __shared__ uint   zs[50][128];
  int tid = threadIdx.x, lane = tid & 63, wv = tid >> 6;   // wv 0..7
  int b = blockIdx.x;
  int ht = b & 15, ct = (b >> 4) & 15, pair = b >> 8;
  int c0 = 2*ct, nc = (ct == 15) ? 1 : 2;
  int h0 = ht * 8;
  int cm1 = c0 ? c0-1 : C_-1;
  int cp  = (c0 + nc) % C_;            // c after tile (wraps)

  // prefetch own-row global state (2 rows per wave; latency hides under phases 0-1)
  int h = h0 + wv;
  long pv0 = ((long)(pair*C_ + c0)*H_ + h)*W_;
  long pv1 = ((long)(pair*C_ + ((nc==2)?c0+1:c0))*H_ + h)*W_;
  long pvm = ((long)(pair*C_ + cm1)*H_ + h)*W_;
  uint pf_vh[2][2], pf_vv[2][2], pf_vs[2][2], pf_vsm0[2], pf_g1[2][2], pf_vvh[2];
  uint2 pf_yw[2][2];
  #pragma unroll
  for (int e = 0; e < 2; ++e){
    int w = lane + 64*e;
    pf_vh[0][e] = *(const uint*)(Vhi + pv0 + w);
    pf_vh[1][e] = *(const uint*)(Vhi + pv1 + w);
    pf_vv[0][e] = *(const uint*)(Vvi + pv0 + w);
    pf_vv[1][e] = *(const uint*)(Vvi + pv1 + w);
    pf_vs[0][e] = *(const uint*)(Vsi + pv0 + w);
    pf_vs[1][e] = *(const uint*)(Vsi + pv1 + w);
    pf_vsm0[e]  = *(const uint*)(Vsi + pvm + w);
    pf_yw[0][e] = YWp[pv0 + w];
    pf_yw[1][e] = YWp[pv1 + w];
    pf_g1[0][e] = *(const uint*)(G1 + pv0 + w);
    pf_g1[1][e] = *(const uint*)(G1 + pv1 + w);
  }
  if (wv < 2){
    int cc = (wv == 0) ? c0 : ((nc==2)? c0+1 : c0);
    long pvh = ((long)(pair*C_ + cc)*H_ + ((h0+H_-1)&(H_-1)))*W_;
    #pragma unroll
    for (int e = 0; e < 2; ++e){
      int w = lane + 64*e;
      pf_vvh[e] = *(const uint*)(Vvi + pvh + w);
    }
  }

  // phase 0: stage A quads. 12 quads x 128 w = 1536 int4, 3 per thread.
  // q 0..3: c0, hq=(2ht-1+q)&31 -> zs[0..15]; q 4..7: c1 -> zs[16..31];
  // q 8..9: cm1, hq=2ht+(q-8) -> zs[32..39]; q 10..11: cp -> zs[40..47].
  const int4* A4 = (const int4*)Ain;
  #pragma unroll
  for (int k = 0; k < 3; ++k){
    int s = tid + 512*k;
    int q = s >> 7, w = s & 127;
    int cc, hq;
    if (q < 4){ cc = c0; hq = (2*ht - 1 + q) & 31; }
    else if (q < 8){ cc = (nc==2) ? c0+1 : c0; hq = (2*ht - 1 + (q-4)) & 31; }
    else if (q < 10){ cc = cm1; hq = 2*ht + (q-8); }
    else { cc = cp; hq = 2*ht + (q-10); }
    union{int4 v; uint e[4];} u;
    u.v = A4[((long)(pair*W_ + w)*C_ + cc)*32 + hq];
    #pragma unroll
    for (int j = 0; j < 4; ++j) zs[4*q + j][w] = u.e[j];
  }
  __syncthreads();

  // phase 1: inverse W-FFT of 36 rows (26 if nc==1), up to 5 per wave batched.
  // zbuf rows: 0..9 c0 (h0-1..h0+8), 10..19 c1, 20..27 cm1 (h0..h0+7), 28..35 cp.
  {
    float2 twi[7]; load_tw(twi_lut, twi, lane);
    float2 ra[5], rb[5];
    #pragma unroll
    for (int k = 0; k < 5; ++k){
      int uu = wv + 8*k;
      int zr;
      if (uu < 10) zr = 3 + uu;
      else if (uu < 20) zr = 19 + (uu - 10);
      else if (uu < 28) zr = 32 + (uu - 20);
      else if (uu < 36) zr = 40 + (uu - 28);
      else zr = 0;
      ra[k] = unpackh2(zs[zr][lane]);
      rb[k] = unpackh2(zs[zr][lane+64]);
    }
    #pragma unroll
    for (int k = 0; k < 5; ++k) fft128_inv(ra[k], rb[k], twi, lane);
    #pragma unroll
    for (int k = 0; k < 5; ++k){
      int uu = wv + 8*k;
      bool act = (uu < 36) && !(nc == 1 && uu >= 10 && uu < 20);
      if (act){ zbuf[uu][lane] = ra[k]; zbuf[uu][lane+64] = rb[k]; }
    }
  }
  __syncthreads();

  // phase 2a: V_{t+1} for own rows (cL=0 and cL=1), X/G1/Q.
  // zs reuse: Vh rr -> zs[rr] (0..15); Vv rr -> zs[16+rr]; Vv halo cL -> zs[32+cL];
  // tbuf rr -> zs[34+rr].
  float2 q2[2][2], vs2[2][2], vsm2[2][2];
  #pragma unroll
  for (int s = 0; s < 2; ++s){
    if (s == 1 && nc == 1) break;
    int rr = wv + 8*s;
    int zb0 = (s == 0) ? (1 + wv) : (11 + wv);         // z(c, h)
    int zbc = (s == 0) ? ((nc==2) ? (11 + wv) : (28 + wv)) : (28 + wv);  // z(c+1, h)
    int zbm = (s == 0) ? (20 + wv) : (1 + wv);          // z(c-1, h)
    long pv = (s == 0) ? pv0 : pv1;
    #pragma unroll
    for (int e = 0; e < 2; ++e){
      int w = lane + 64*e;
      float2 z0 = zbuf[zb0][w];
      float2 zw = zbuf[zb0][(w+1)&(W_-1)];
      float2 zh = zbuf[zb0+1][w];
      float2 zc = zbuf[zbc][w];
      float2 zm = zbuf[zbm][w];
      float2 vh  = vupd(make_float2(z0.x-zw.x, z0.y-zw.y), unpackh2(pf_vh[s][e]), thrn);
      float2 vv  = vupd(make_float2(z0.x-zh.x, z0.y-zh.y), unpackh2(pf_vv[s][e]), thrn);
      float2 vsl = vupd(make_float2(z0.x-zc.x, z0.y-zc.y), unpackh2(pf_vs[s][e]), thrn);
      if (s == 0){
        vsm2[0][e] = vupd(make_float2(zm.x-z0.x, zm.y-z0.y), unpackh2(pf_vsm0[e]), thrn);
        vsm2[1][e] = vsl;     // Vs(c0) is cL=1's (c-1) term
      }
      Vho[pv+w] = __floats2half2_rn(vh.x, vh.y);
      Vvo[pv+w] = __floats2half2_rn(vv.x, vv.y);
      Vso[pv+w] = __floats2half2_rn(vsl.x, vsl.y);
      zs[rr][w]    = packh2(vh);
      zs[16+rr][w] = packh2(vv);
      vs2[s][e] = vsl;
      float2 a0 = unpackh2(pf_yw[s][e].x);
      float2 a1 = unpackh2(pf_yw[s][e].y);
      float2 g1 = firstG ? make_float2(0.0f, 0.0f) : unpackh2(pf_g1[s][e]);
      float x0 = (a0.y*a0.x + mu*z0.x - g1.x) / (a0.y + mu);
      float x1 = (a1.y*a1.x + mu*z0.y - g1.y) / (a1.y + mu);
      float g10 = g1.x + mu*(x0 - z0.x);
      float g11 = g1.y + mu*(x1 - z0.y);
      G1[pv+w] = __floats2half2_rn(g10, g11);
      q2[s][e] = make_float2(x0 + g10*invmun, x1 + g11*invmun);
    }
  }
  if (wv < 2 && !(wv == 1 && nc == 1)){
    int zb = (wv == 0) ? 0 : 10;
    #pragma unroll
    for (int e = 0; e < 2; ++e){
      int w = lane + 64*e;
      float2 z0 = zbuf[zb][w], zh = zbuf[zb+1][w];
      float2 vvm = vupd(make_float2(z0.x-zh.x, z0.y-zh.y), unpackh2(pf_vvh[e]), thrn);
      zs[32+wv][w] = packh2(vvm);
    }
  }
  __syncthreads();

  // phase 2b: numer + forward W-FFT (2 rows per wave, batched)
  {
    float2 twf[7]; load_tw(twf_lut, twf, lane);
    float2 nm[2][2];
    #pragma unroll
    for (int s = 0; s < 2; ++s){
      int rr = wv + 8*s;
      #pragma unroll
      for (int e = 0; e < 2; ++e){
        int w = lane + 64*e;
        float2 vh  = unpackh2(zs[rr][w]);
        float2 vhm = unpackh2(zs[rr][(w+W_-1)&(W_-1)]);
        float2 vv  = unpackh2(zs[16+rr][w]);
        float2 vvm = (wv == 0) ? unpackh2(zs[32+s][w]) : unpackh2(zs[16+rr-1][w]);
        nm[s][e] = make_float2(q2[s][e].x + (vh.x-vhm.x) + (vv.x-vvm.x) + (vs2[s][e].x - vsm2[s][e].x),
                               q2[s][e].y + (vh.y-vhm.y) + (vv.y-vvm.y) + (vs2[s][e].y - vsm2[s][e].y));
      }
    }
    fft128_fwd(nm[0][0], nm[0][1], twf, lane);
    fft128_fwd(nm[1][0], nm[1][1], twf, lane);
    zs[34+wv][lane]      = packh2(nm[0][0]);
    zs[34+wv][lane+64]   = packh2(nm[0][1]);
    if (nc == 2){
      zs[42+wv][lane]    = packh2(nm[1][0]);
      zs[42+wv][lane+64] = packh2(nm[1][1]);
    }
  }
  __syncthreads();

  // phase 3: store own quads. 4 quads (2 per c) x 128 w = 512 int4, 1 per thread.
  {
    int q = tid >> 7, w = tid & 127;
    int cL = q >> 1, hq2 = q & 1;
    if (cL < nc){
      int4* Ao4 = (int4*)Aout;
      union{int4 v; uint e[4];} uo;
      #pragma unroll
      for (int j = 0; j < 4; ++j) uo.e[j] = zs[34 + 8*cL + 4*hq2 + j][w];
      Ao4[((long)(pair*W_ + w)*C_ + (c0+cL))*32 + 2*ht + hq2] = uo.v;
    }
  }
}

// K4: final: iW-FFT own rows only -> Z fp32.
__global__ __launch_bounds__(256) void kern_last(const __half2* __restrict__ A,
    float* __restrict__ Z, const float2* __restrict__ twi_lut)
{
  __shared__ uint zs[8][128];
  int tid = threadIdx.x, lane = tid & 63, wv = tid >> 6;
  int b = blockIdx.x;
  int ht = b & 15, c = (b >> 4) % C_, pair = b / (16*C_);
  int h0 = ht * 8;
  const int4* A4 = (const int4*)A;
  {
    int p = tid >> 1, hq = tid & 1;
    union{int4 v; uint e[4];} u;
    u.v = A4[((long)(pair*W_ + p)*C_ + c)*32 + 2*ht + hq];
    #pragma unroll
    for (int j = 0; j < 4; ++j) zs[4*hq + j][p] = u.e[j];
  }
  __syncthreads();
  float2 twi[7]; load_tw(twi_lut, twi, lane);
  long v0 = (long)(2*pair)*CV_, v1 = v0 + CV_;
  #pragma unroll
  for (int r = 0; r < 2; ++r){
    int i = wv + 4*r, h = h0 + i;
    float2 a = unpackh2(zs[i][lane]);
    float2 bb = unpackh2(zs[i][lane+64]);
    fft128_inv(a, bb, twi, lane);
    long rb = ((long)c*H_ + h)*W_;
    Z[v0+rb+lane]    = a.x;  Z[v1+rb+lane]    = a.y;
    Z[v0+rb+lane+64] = bb.x; Z[v1+rb+lane+64] = bb.y;
  }
}

extern "C" void kernel_launch(void* const* d_in, const int* in_sizes, int n_in,
                              void* d_out, int out_size, void* d_ws, size_t ws_size,
                              hipStream_t stream)
{
  const float* Y   = (const float*)d_in[0];
  const float* inW = (const float*)d_in[1];
  float* Z = (float*)d_out;

  float2* twf_lut = (float2*)d_ws;
  float2* twi_lut = twf_lut + 7*64;
  float*  dtab    = (float*)(twi_lut + 7*64);
  char*   fields  = (char*)d_ws + 8192;

  const int HT = TOTAL/2;
  uint2*   YWp = (uint2*)fields;
  __half2* G1  = (__half2*)(YWp + HT);
  __half2* Vh0 = G1  + HT;
  __half2* Vv0 = Vh0 + HT;
  __half2* Vs0 = Vv0 + HT;
  __half2* Vh1 = Vs0 + HT;
  __half2* Vv1 = Vh1 + HT;
  __half2* Vs1 = Vv1 + HT;
  __half2* A0  = Vs1 + HT;
  __half2* A1  = A0  + HT;
  __half2* Vh[2] = {Vh0, Vh1};
  __half2* Vv[2] = {Vv0, Vv1};
  __half2* Vs[2] = {Vs0, Vs1};
  __half2* Ab[2] = {A0, A1};

  kern_init<<<dim3(1), dim3(128), 0, stream>>>(twf_lut, twi_lut, dtab);
  kern_pack<<<dim3(2*CV_/256), dim3(256), 0, stream>>>(Y, inW, YWp);
  kern_fwd0<<<dim3(2*C_*16), dim3(256), 0, stream>>>(Y, Vh0, Vv0, Vs0, A0, 1.0f, twf_lut);

  float mu = 0.1f;
  for (int t = 0; t < 19; ++t){
    kern_CH<<<dim3(2*W_), dim3(1024), 0, stream>>>(Ab[t&1], twf_lut, twi_lut, dtab);
    float mun = mu * RHO_F;
    kern_CA<<<dim3(512), dim3(512), 0, stream>>>(
        Ab[t&1], Ab[(t+1)&1],
        Vh[t&1], Vv[t&1], Vs[t&1],
        Vh[(t+1)&1], Vv[(t+1)&1], Vs[(t+1)&1],
        YWp, G1, mu, 0.1f/mun, 1.0f/mun, (t==0) ? 1 : 0,
        twf_lut, twi_lut);
    mu = mun;
  }
  kern_CH<<<dim3(2*W_), dim3(1024), 0, stream>>>(Ab[1], twf_lut, twi_lut, dtab);
  kern_last<<<dim3(2*C_*16), dim3(256), 0, stream>>>(Ab[1], Z, twi_lut);
}